// Round 1
// baseline (27063.733 us; speedup 1.0000x reference)
//
#include <hip/hip_runtime.h>
#include <cstdint>
#include <cmath>

#define U_ 40000
#define I_ 40000
#define C_ 5
#define D_ 128
#define A_ 64
#define L_ 2
#define E_ 1280000
#define N_ (U_ + I_)

// ---------------------------------------------------------------------------
// init: bank (=d_out[0..N*C*D)) = ego = concat(user, item); zero pad row
// ---------------------------------------------------------------------------
__global__ __launch_bounds__(256) void init_kernel(
    const float* __restrict__ user, const float* __restrict__ item,
    float* __restrict__ bank, float* __restrict__ ego)
{
    size_t i = (size_t)blockIdx.x * 256 + threadIdx.x;   // float4 index
    const size_t total4 = (size_t)N_ * C_ * D_ / 4;
    const size_t user4  = (size_t)U_ * C_ * D_ / 4;
    if (i < total4) {
        float4 v = (i < user4) ? ((const float4*)user)[i]
                               : ((const float4*)item)[i - user4];
        ((float4*)bank)[i] = v;
        ((float4*)ego)[i]  = v;
    }
    if (blockIdx.x == 0 && threadIdx.x < C_ * D_ / 4) {
        ((float4*)bank)[total4 + threadIdx.x] = make_float4(0.f, 0.f, 0.f, 0.f);
    }
}

// ---------------------------------------------------------------------------
// crit chain: crit1 = crit0@CL0, crit2 = crit1@CL1, means -> d_out tail
// ---------------------------------------------------------------------------
__global__ __launch_bounds__(128) void crit_kernel(
    const float* __restrict__ crit0, const float* __restrict__ clayers,
    float* __restrict__ crit1, float* __restrict__ crit2,
    float* __restrict__ crit_means)
{
    __shared__ float c0[C_ * D_], c1[C_ * D_], c2[C_ * D_];
    int t = threadIdx.x;   // 0..127 = output column
    for (int i = t; i < C_ * D_; i += 128) c0[i] = crit0[i];
    __syncthreads();
    for (int c = 0; c < C_; ++c) {
        float acc = 0.f;
        for (int d = 0; d < D_; ++d) acc = fmaf(c0[c * D_ + d], clayers[d * D_ + t], acc);
        c1[c * D_ + t] = acc;
    }
    __syncthreads();
    for (int c = 0; c < C_; ++c) {
        float acc = 0.f;
        for (int d = 0; d < D_; ++d) acc = fmaf(c1[c * D_ + d], clayers[D_ * D_ + d * D_ + t], acc);
        c2[c * D_ + t] = acc;
    }
    __syncthreads();
    for (int i = t; i < C_ * D_; i += 128) {
        crit1[i] = c1[i];
        crit2[i] = c2[i];
        crit_means[i] = (c0[i] + c1[i] + c2[i]) * (1.0f / 3.0f);
    }
}

// ---------------------------------------------------------------------------
// scatter: gf[rows[c][e], c, :] += vals[c][e] * ego[cols[c][e], c, :]
// half-wave (32 lanes) per edge, float4 per lane, fp32 atomics
// ---------------------------------------------------------------------------
__global__ __launch_bounds__(256) void scatter_kernel(
    const float* __restrict__ ego, const float* __restrict__ vals,
    const int* __restrict__ rows, const int* __restrict__ cols,
    float* __restrict__ gf)
{
    size_t gt = (size_t)blockIdx.x * 256 + threadIdx.x;
    uint32_t eid = (uint32_t)(gt >> 5);       // global edge id in [0, C*E)
    int lane = (int)(gt & 31);
    uint32_t c = eid / (uint32_t)E_;
    float v  = vals[eid];
    int  src = cols[eid];
    int  dst = rows[eid];
    const float4* sp = (const float4*)(ego + ((size_t)src * C_ + c) * D_);
    float4 m = sp[lane];
    float* dp = gf + ((size_t)dst * C_ + c) * D_ + lane * 4;
    atomicAdd(dp + 0, v * m.x);
    atomicAdd(dp + 1, v * m.y);
    atomicAdd(dp + 2, v * m.z);
    atomicAdd(dp + 3, v * m.w);
}

// ---------------------------------------------------------------------------
// rowgemm: per (n,c) row r: y = row@W; z = y*crit[c]; s = leaky(z@G)
// in-place on buf. W,G staged in LDS (64KB each). 4 waves/block, wave=1 row.
// ---------------------------------------------------------------------------
__global__ __launch_bounds__(256) void rowgemm_kernel(
    float* __restrict__ buf,
    const float* __restrict__ W, const float* __restrict__ G,
    const float* __restrict__ critv)
{
    __shared__ float Wl[D_ * D_];
    __shared__ float Gl[D_ * D_];
    __shared__ float rb[4][D_];
    for (int i = threadIdx.x; i < D_ * D_; i += 256) { Wl[i] = W[i]; Gl[i] = G[i]; }
    __syncthreads();
    int wave = threadIdx.x >> 6, lane = threadIdx.x & 63;
    int gw = blockIdx.x * 4 + wave, nw = gridDim.x * 4;
    const int rows_total = N_ * C_;
    int iters = (rows_total + nw - 1) / nw;
    for (int it = 0; it < iters; ++it) {
        int r = gw + it * nw;
        bool act = r < rows_total;
        float r0 = 0.f, r1 = 0.f;
        if (act) { r0 = buf[(size_t)r * D_ + lane]; r1 = buf[(size_t)r * D_ + lane + 64]; }
        rb[wave][lane] = r0; rb[wave][lane + 64] = r1;
        __syncthreads();
        float y0 = 0.f, y1 = 0.f;
        for (int d = 0; d < D_; d += 4) {
            float4 rv = *(const float4*)&rb[wave][d];
            y0 = fmaf(rv.x, Wl[(d + 0) * D_ + lane], y0); y1 = fmaf(rv.x, Wl[(d + 0) * D_ + lane + 64], y1);
            y0 = fmaf(rv.y, Wl[(d + 1) * D_ + lane], y0); y1 = fmaf(rv.y, Wl[(d + 1) * D_ + lane + 64], y1);
            y0 = fmaf(rv.z, Wl[(d + 2) * D_ + lane], y0); y1 = fmaf(rv.z, Wl[(d + 2) * D_ + lane + 64], y1);
            y0 = fmaf(rv.w, Wl[(d + 3) * D_ + lane], y0); y1 = fmaf(rv.w, Wl[(d + 3) * D_ + lane + 64], y1);
        }
        __syncthreads();
        int c = act ? (r % C_) : 0;
        float z0 = 0.f, z1 = 0.f;
        if (act) { z0 = y0 * critv[c * D_ + lane]; z1 = y1 * critv[c * D_ + lane + 64]; }
        rb[wave][lane] = z0; rb[wave][lane + 64] = z1;
        __syncthreads();
        float s0 = 0.f, s1 = 0.f;
        for (int d = 0; d < D_; d += 4) {
            float4 zv = *(const float4*)&rb[wave][d];
            s0 = fmaf(zv.x, Gl[(d + 0) * D_ + lane], s0); s1 = fmaf(zv.x, Gl[(d + 0) * D_ + lane + 64], s1);
            s0 = fmaf(zv.y, Gl[(d + 1) * D_ + lane], s0); s1 = fmaf(zv.y, Gl[(d + 1) * D_ + lane + 64], s1);
            s0 = fmaf(zv.z, Gl[(d + 2) * D_ + lane], s0); s1 = fmaf(zv.z, Gl[(d + 2) * D_ + lane + 64], s1);
            s0 = fmaf(zv.w, Gl[(d + 3) * D_ + lane], s0); s1 = fmaf(zv.w, Gl[(d + 3) * D_ + lane + 64], s1);
        }
        __syncthreads();
        if (act) {
            s0 = s0 > 0.f ? s0 : 0.01f * s0;
            s1 = s1 > 0.f ? s1 : 0.01f * s1;
            buf[(size_t)r * D_ + lane] = s0;
            buf[(size_t)r * D_ + lane + 64] = s1;
        }
    }
}

// ---------------------------------------------------------------------------
// attention: per node n (one wave): h=tanh(S@p1[k]), raw=h.p2[k],
// softmax over c, ego[n,k,:]=sum_c w*S[c,:]; bank += ego (last: /3)
// ---------------------------------------------------------------------------
__global__ __launch_bounds__(256) void attn_kernel(
    const float* __restrict__ stacked, const float* __restrict__ p1,
    const float* __restrict__ p2, float* __restrict__ ego,
    float* __restrict__ bank, int last)
{
    __shared__ float sst[4][C_][D_];
    int wave = threadIdx.x >> 6, lane = threadIdx.x & 63;
    int gw = blockIdx.x * 4 + wave, nw = gridDim.x * 4;
    int iters = (N_ + nw - 1) / nw;
    for (int it = 0; it < iters; ++it) {
        int n = gw + it * nw;
        bool act = n < N_;
        for (int c = 0; c < C_; ++c) {
            float t0 = 0.f, t1 = 0.f;
            if (act) {
                t0 = stacked[((size_t)n * C_ + c) * D_ + lane];
                t1 = stacked[((size_t)n * C_ + c) * D_ + lane + 64];
            }
            sst[wave][c][lane] = t0;
            sst[wave][c][lane + 64] = t1;
        }
        __syncthreads();
        for (int k = 0; k < C_; ++k) {
            float acc[C_] = {0.f, 0.f, 0.f, 0.f, 0.f};
            const float* p1k = p1 + (size_t)k * D_ * A_;
            for (int d = 0; d < D_; d += 2) {
                float pv0 = p1k[(d + 0) * A_ + lane];
                float pv1 = p1k[(d + 1) * A_ + lane];
                #pragma unroll
                for (int c = 0; c < C_; ++c) {
                    float2 sv = *(const float2*)&sst[wave][c][d];
                    acc[c] = fmaf(sv.x, pv0, acc[c]);
                    acc[c] = fmaf(sv.y, pv1, acc[c]);
                }
            }
            float raw[C_];
            float pw = p2[k * A_ + lane];
            #pragma unroll
            for (int c = 0; c < C_; ++c) {
                float pr = tanhf(acc[c]) * pw;
                #pragma unroll
                for (int off = 32; off; off >>= 1) pr += __shfl_xor(pr, off);
                raw[c] = pr;
            }
            float m = raw[0];
            #pragma unroll
            for (int c = 1; c < C_; ++c) m = fmaxf(m, raw[c]);
            float s = 0.f, w[C_];
            #pragma unroll
            for (int c = 0; c < C_; ++c) { w[c] = __expf(raw[c] - m); s += w[c]; }
            float inv = 1.0f / s;
            float e0 = 0.f, e1 = 0.f;
            #pragma unroll
            for (int c = 0; c < C_; ++c) {
                float wc = w[c] * inv;
                e0 = fmaf(wc, sst[wave][c][lane], e0);
                e1 = fmaf(wc, sst[wave][c][lane + 64], e1);
            }
            if (act) {
                size_t o = ((size_t)n * C_ + k) * D_ + lane;
                ego[o] = e0; ego[o + 64] = e1;
                float b0 = bank[o] + e0, b1 = bank[o + 64] + e1;
                if (last) { b0 *= (1.0f / 3.0f); b1 *= (1.0f / 3.0f); }
                bank[o] = b0; bank[o + 64] = b1;
            }
        }
        __syncthreads();
    }
}

extern "C" void kernel_launch(void* const* d_in, const int* in_sizes, int n_in,
                              void* d_out, int out_size, void* d_ws, size_t ws_size,
                              hipStream_t stream) {
    const float* user  = (const float*)d_in[0];
    const float* item  = (const float*)d_in[1];
    const float* crit0 = (const float*)d_in[2];
    const float* W     = (const float*)d_in[3];
    const float* gl    = (const float*)d_in[4];
    const float* cl    = (const float*)d_in[5];
    const float* p1    = (const float*)d_in[6];
    const float* p2    = (const float*)d_in[7];
    const float* vals  = (const float*)d_in[8];
    const int*   rows  = (const int*)d_in[9];
    const int*   cols  = (const int*)d_in[10];

    float* out  = (float*)d_out;
    float* bank = out;                                  // bank lives in d_out
    float* crit_means = out + (size_t)(N_ + 1) * C_ * D_;

    float* ego   = (float*)d_ws;                        // (N,C,D) fp32
    float* buf   = ego + (size_t)N_ * C_ * D_;          // gf / stacked (N,C,D)
    float* crit1 = buf + (size_t)N_ * C_ * D_;
    float* crit2 = crit1 + C_ * D_;

    init_kernel<<<(N_ * C_ * D_ / 4 + 255) / 256, 256, 0, stream>>>(user, item, bank, ego);
    crit_kernel<<<1, 128, 0, stream>>>(crit0, cl, crit1, crit2, crit_means);

    for (int l = 0; l < L_; ++l) {
        hipMemsetAsync(buf, 0, (size_t)N_ * C_ * D_ * sizeof(float), stream);
        scatter_kernel<<<(size_t)C_ * E_ * 32 / 256, 256, 0, stream>>>(ego, vals, rows, cols, buf);
        rowgemm_kernel<<<256, 256, 0, stream>>>(buf, W, gl + (size_t)l * D_ * D_,
                                                l == 0 ? crit0 : crit1);
        attn_kernel<<<1024, 256, 0, stream>>>(buf, p1, p2, ego, bank, l == L_ - 1 ? 1 : 0);
    }
}

// Round 2
// 7468.304 us; speedup vs baseline: 3.6238x; 3.6238x over previous
//
#include <hip/hip_runtime.h>
#include <cstdint>
#include <cmath>

#define U_ 40000
#define I_ 40000
#define C_ 5
#define D_ 128
#define A_ 64
#define L_ 2
#define E_ 1280000
#define N_ (U_ + I_)
#define BINS_ (N_ * C_)

// ---------------------------------------------------------------------------
// init: bank (=d_out[0..N*C*D)) = ego = concat(user, item); zero pad row
// ---------------------------------------------------------------------------
__global__ __launch_bounds__(256) void init_kernel(
    const float* __restrict__ user, const float* __restrict__ item,
    float* __restrict__ bank, float* __restrict__ ego)
{
    size_t i = (size_t)blockIdx.x * 256 + threadIdx.x;   // float4 index
    const size_t total4 = (size_t)N_ * C_ * D_ / 4;
    const size_t user4  = (size_t)U_ * C_ * D_ / 4;
    if (i < total4) {
        float4 v = (i < user4) ? ((const float4*)user)[i]
                               : ((const float4*)item)[i - user4];
        ((float4*)bank)[i] = v;
        ((float4*)ego)[i]  = v;
    }
    if (blockIdx.x == 0 && threadIdx.x < C_ * D_ / 4) {
        ((float4*)bank)[total4 + threadIdx.x] = make_float4(0.f, 0.f, 0.f, 0.f);
    }
}

// ---------------------------------------------------------------------------
// crit chain: crit1 = crit0@CL0, crit2 = crit1@CL1, means -> d_out tail
// ---------------------------------------------------------------------------
__global__ __launch_bounds__(128) void crit_kernel(
    const float* __restrict__ crit0, const float* __restrict__ clayers,
    float* __restrict__ crit1, float* __restrict__ crit2,
    float* __restrict__ crit_means)
{
    __shared__ float c0[C_ * D_], c1[C_ * D_], c2[C_ * D_];
    int t = threadIdx.x;   // 0..127 = output column
    for (int i = t; i < C_ * D_; i += 128) c0[i] = crit0[i];
    __syncthreads();
    for (int c = 0; c < C_; ++c) {
        float acc = 0.f;
        for (int d = 0; d < D_; ++d) acc = fmaf(c0[c * D_ + d], clayers[d * D_ + t], acc);
        c1[c * D_ + t] = acc;
    }
    __syncthreads();
    for (int c = 0; c < C_; ++c) {
        float acc = 0.f;
        for (int d = 0; d < D_; ++d) acc = fmaf(c1[c * D_ + d], clayers[D_ * D_ + d * D_ + t], acc);
        c2[c * D_ + t] = acc;
    }
    __syncthreads();
    for (int i = t; i < C_ * D_; i += 128) {
        crit1[i] = c1[i];
        crit2[i] = c2[i];
        crit_means[i] = (c0[i] + c1[i] + c2[i]) * (1.0f / 3.0f);
    }
}

// ---------------------------------------------------------------------------
// CSR build: hist -> 3-kernel exclusive scan -> fill perm (by dest bin)
// bin = row * C + c
// ---------------------------------------------------------------------------
__global__ __launch_bounds__(256) void hist_kernel(
    const int* __restrict__ rows, int* __restrict__ cnt)
{
    int eid = blockIdx.x * 256 + threadIdx.x;       // C*E = 6.4M, exact grid
    int c = eid / E_;
    int bin = rows[eid] * C_ + c;
    atomicAdd(&cnt[bin], 1);
}

__global__ __launch_bounds__(256) void scanA_kernel(
    const int* __restrict__ cnt, int* __restrict__ bin_start,
    int* __restrict__ blocksum)
{
    __shared__ int lsum[256];
    int b = blockIdx.x, t = threadIdx.x;
    int base = b * 1024 + t * 4;
    int v[4];
    #pragma unroll
    for (int i = 0; i < 4; ++i) v[i] = (base + i < BINS_) ? cnt[base + i] : 0;
    int s = v[0] + v[1] + v[2] + v[3];
    lsum[t] = s;
    __syncthreads();
    for (int off = 1; off < 256; off <<= 1) {
        int x = (t >= off) ? lsum[t - off] : 0;
        __syncthreads();
        lsum[t] += x;
        __syncthreads();
    }
    int excl = lsum[t] - s;
    if (t == 255) blocksum[b] = lsum[255];
    #pragma unroll
    for (int i = 0; i < 4; ++i) {
        if (base + i < BINS_) bin_start[base + i] = excl;
        excl += v[i];
    }
}

__global__ void scanB_kernel(int* __restrict__ blocksum, int nb)
{
    if (threadIdx.x == 0 && blockIdx.x == 0) {
        int acc = 0;
        for (int b = 0; b < nb; ++b) { int v = blocksum[b]; blocksum[b] = acc; acc += v; }
    }
}

__global__ __launch_bounds__(256) void scanC_kernel(
    int* __restrict__ bin_start, const int* __restrict__ blocksum)
{
    int b = blockIdx.x, t = threadIdx.x;
    int off = blocksum[b];
    int base = b * 1024 + t * 4;
    #pragma unroll
    for (int i = 0; i < 4; ++i)
        if (base + i < BINS_) bin_start[base + i] += off;
    if (b == 0 && t == 0) bin_start[BINS_] = C_ * E_;
}

__global__ __launch_bounds__(256) void fill_kernel(
    const int* __restrict__ rows, const int* __restrict__ bin_start,
    int* __restrict__ cursor, int* __restrict__ perm)
{
    int eid = blockIdx.x * 256 + threadIdx.x;
    int c = eid / E_;
    int bin = rows[eid] * C_ + c;
    int pos = bin_start[bin] + atomicAdd(&cursor[bin], 1);
    perm[pos] = eid;
}

// ---------------------------------------------------------------------------
// gather: one wave per dest bin (n,c): gf[bin,:] = sum_e vals[e]*ego[cols[e],c,:]
// wave-uniform meta loads (scalar), float2/lane payload, no atomics
// ---------------------------------------------------------------------------
__global__ __launch_bounds__(256) void gather_kernel(
    const float* __restrict__ ego, const float* __restrict__ vals,
    const int* __restrict__ cols, const int* __restrict__ bin_start,
    const int* __restrict__ perm, float* __restrict__ gf)
{
    int w = (int)(((size_t)blockIdx.x * 256 + threadIdx.x) >> 6);
    int lane = threadIdx.x & 63;
    w = __builtin_amdgcn_readfirstlane(w);      // wave-uniform bin id
    int bs = bin_start[w], be = bin_start[w + 1];
    int c = w % C_;
    float2 acc = make_float2(0.f, 0.f);
    int i = bs;
    for (; i + 1 < be; i += 2) {                // 2-way ILP on the dep chain
        int e0 = perm[i], e1 = perm[i + 1];
        float v0 = vals[e0], v1 = vals[e1];
        int s0 = cols[e0], s1 = cols[e1];
        const float2* p0 = (const float2*)(ego + ((size_t)s0 * C_ + c) * D_);
        const float2* p1 = (const float2*)(ego + ((size_t)s1 * C_ + c) * D_);
        float2 m0 = p0[lane], m1 = p1[lane];
        acc.x = fmaf(v0, m0.x, acc.x); acc.y = fmaf(v0, m0.y, acc.y);
        acc.x = fmaf(v1, m1.x, acc.x); acc.y = fmaf(v1, m1.y, acc.y);
    }
    if (i < be) {
        int e0 = perm[i];
        float v0 = vals[e0]; int s0 = cols[e0];
        const float2* p0 = (const float2*)(ego + ((size_t)s0 * C_ + c) * D_);
        float2 m0 = p0[lane];
        acc.x = fmaf(v0, m0.x, acc.x); acc.y = fmaf(v0, m0.y, acc.y);
    }
    ((float2*)(gf + (size_t)w * D_))[lane] = acc;
}

// ---------------------------------------------------------------------------
// fallback scatter (only if ws too small for CSR): fp32 atomics
// ---------------------------------------------------------------------------
__global__ __launch_bounds__(256) void scatter_kernel(
    const float* __restrict__ ego, const float* __restrict__ vals,
    const int* __restrict__ rows, const int* __restrict__ cols,
    float* __restrict__ gf)
{
    size_t gt = (size_t)blockIdx.x * 256 + threadIdx.x;
    uint32_t eid = (uint32_t)(gt >> 5);
    int lane = (int)(gt & 31);
    uint32_t c = eid / (uint32_t)E_;
    float v  = vals[eid];
    int  src = cols[eid];
    int  dst = rows[eid];
    const float4* sp = (const float4*)(ego + ((size_t)src * C_ + c) * D_);
    float4 m = sp[lane];
    float* dp = gf + ((size_t)dst * C_ + c) * D_ + lane * 4;
    atomicAdd(dp + 0, v * m.x);
    atomicAdd(dp + 1, v * m.y);
    atomicAdd(dp + 2, v * m.z);
    atomicAdd(dp + 3, v * m.w);
}

// ---------------------------------------------------------------------------
// rowgemm: per (n,c) row r: y = row@W; z = y*crit[c]; s = leaky(z@G)
// ---------------------------------------------------------------------------
__global__ __launch_bounds__(256) void rowgemm_kernel(
    float* __restrict__ buf,
    const float* __restrict__ W, const float* __restrict__ G,
    const float* __restrict__ critv)
{
    __shared__ float Wl[D_ * D_];
    __shared__ float Gl[D_ * D_];
    __shared__ float rb[4][D_];
    for (int i = threadIdx.x; i < D_ * D_; i += 256) { Wl[i] = W[i]; Gl[i] = G[i]; }
    __syncthreads();
    int wave = threadIdx.x >> 6, lane = threadIdx.x & 63;
    int gw = blockIdx.x * 4 + wave, nw = gridDim.x * 4;
    const int rows_total = N_ * C_;
    int iters = (rows_total + nw - 1) / nw;
    for (int it = 0; it < iters; ++it) {
        int r = gw + it * nw;
        bool act = r < rows_total;
        float r0 = 0.f, r1 = 0.f;
        if (act) { r0 = buf[(size_t)r * D_ + lane]; r1 = buf[(size_t)r * D_ + lane + 64]; }
        rb[wave][lane] = r0; rb[wave][lane + 64] = r1;
        __syncthreads();
        float y0 = 0.f, y1 = 0.f;
        for (int d = 0; d < D_; d += 4) {
            float4 rv = *(const float4*)&rb[wave][d];
            y0 = fmaf(rv.x, Wl[(d + 0) * D_ + lane], y0); y1 = fmaf(rv.x, Wl[(d + 0) * D_ + lane + 64], y1);
            y0 = fmaf(rv.y, Wl[(d + 1) * D_ + lane], y0); y1 = fmaf(rv.y, Wl[(d + 1) * D_ + lane + 64], y1);
            y0 = fmaf(rv.z, Wl[(d + 2) * D_ + lane], y0); y1 = fmaf(rv.z, Wl[(d + 2) * D_ + lane + 64], y1);
            y0 = fmaf(rv.w, Wl[(d + 3) * D_ + lane], y0); y1 = fmaf(rv.w, Wl[(d + 3) * D_ + lane + 64], y1);
        }
        __syncthreads();
        int c = act ? (r % C_) : 0;
        float z0 = 0.f, z1 = 0.f;
        if (act) { z0 = y0 * critv[c * D_ + lane]; z1 = y1 * critv[c * D_ + lane + 64]; }
        rb[wave][lane] = z0; rb[wave][lane + 64] = z1;
        __syncthreads();
        float s0 = 0.f, s1 = 0.f;
        for (int d = 0; d < D_; d += 4) {
            float4 zv = *(const float4*)&rb[wave][d];
            s0 = fmaf(zv.x, Gl[(d + 0) * D_ + lane], s0); s1 = fmaf(zv.x, Gl[(d + 0) * D_ + lane + 64], s1);
            s0 = fmaf(zv.y, Gl[(d + 1) * D_ + lane], s0); s1 = fmaf(zv.y, Gl[(d + 1) * D_ + lane + 64], s1);
            s0 = fmaf(zv.z, Gl[(d + 2) * D_ + lane], s0); s1 = fmaf(zv.z, Gl[(d + 2) * D_ + lane + 64], s1);
            s0 = fmaf(zv.w, Gl[(d + 3) * D_ + lane], s0); s1 = fmaf(zv.w, Gl[(d + 3) * D_ + lane + 64], s1);
        }
        __syncthreads();
        if (act) {
            s0 = s0 > 0.f ? s0 : 0.01f * s0;
            s1 = s1 > 0.f ? s1 : 0.01f * s1;
            buf[(size_t)r * D_ + lane] = s0;
            buf[(size_t)r * D_ + lane + 64] = s1;
        }
    }
}

// ---------------------------------------------------------------------------
// attention
// ---------------------------------------------------------------------------
__global__ __launch_bounds__(256) void attn_kernel(
    const float* __restrict__ stacked, const float* __restrict__ p1,
    const float* __restrict__ p2, float* __restrict__ ego,
    float* __restrict__ bank, int last)
{
    __shared__ float sst[4][C_][D_];
    int wave = threadIdx.x >> 6, lane = threadIdx.x & 63;
    int gw = blockIdx.x * 4 + wave, nw = gridDim.x * 4;
    int iters = (N_ + nw - 1) / nw;
    for (int it = 0; it < iters; ++it) {
        int n = gw + it * nw;
        bool act = n < N_;
        for (int c = 0; c < C_; ++c) {
            float t0 = 0.f, t1 = 0.f;
            if (act) {
                t0 = stacked[((size_t)n * C_ + c) * D_ + lane];
                t1 = stacked[((size_t)n * C_ + c) * D_ + lane + 64];
            }
            sst[wave][c][lane] = t0;
            sst[wave][c][lane + 64] = t1;
        }
        __syncthreads();
        for (int k = 0; k < C_; ++k) {
            float acc[C_] = {0.f, 0.f, 0.f, 0.f, 0.f};
            const float* p1k = p1 + (size_t)k * D_ * A_;
            for (int d = 0; d < D_; d += 2) {
                float pv0 = p1k[(d + 0) * A_ + lane];
                float pv1 = p1k[(d + 1) * A_ + lane];
                #pragma unroll
                for (int c = 0; c < C_; ++c) {
                    float2 sv = *(const float2*)&sst[wave][c][d];
                    acc[c] = fmaf(sv.x, pv0, acc[c]);
                    acc[c] = fmaf(sv.y, pv1, acc[c]);
                }
            }
            float raw[C_];
            float pw = p2[k * A_ + lane];
            #pragma unroll
            for (int c = 0; c < C_; ++c) {
                float pr = tanhf(acc[c]) * pw;
                #pragma unroll
                for (int off = 32; off; off >>= 1) pr += __shfl_xor(pr, off);
                raw[c] = pr;
            }
            float m = raw[0];
            #pragma unroll
            for (int c = 1; c < C_; ++c) m = fmaxf(m, raw[c]);
            float s = 0.f, w[C_];
            #pragma unroll
            for (int c = 0; c < C_; ++c) { w[c] = __expf(raw[c] - m); s += w[c]; }
            float inv = 1.0f / s;
            float e0 = 0.f, e1 = 0.f;
            #pragma unroll
            for (int c = 0; c < C_; ++c) {
                float wc = w[c] * inv;
                e0 = fmaf(wc, sst[wave][c][lane], e0);
                e1 = fmaf(wc, sst[wave][c][lane + 64], e1);
            }
            if (act) {
                size_t o = ((size_t)n * C_ + k) * D_ + lane;
                ego[o] = e0; ego[o + 64] = e1;
                float b0 = bank[o] + e0, b1 = bank[o + 64] + e1;
                if (last) { b0 *= (1.0f / 3.0f); b1 *= (1.0f / 3.0f); }
                bank[o] = b0; bank[o + 64] = b1;
            }
        }
        __syncthreads();
    }
}

extern "C" void kernel_launch(void* const* d_in, const int* in_sizes, int n_in,
                              void* d_out, int out_size, void* d_ws, size_t ws_size,
                              hipStream_t stream) {
    const float* user  = (const float*)d_in[0];
    const float* item  = (const float*)d_in[1];
    const float* crit0 = (const float*)d_in[2];
    const float* W     = (const float*)d_in[3];
    const float* gl    = (const float*)d_in[4];
    const float* cl    = (const float*)d_in[5];
    const float* p1    = (const float*)d_in[6];
    const float* p2    = (const float*)d_in[7];
    const float* vals  = (const float*)d_in[8];
    const int*   rows  = (const int*)d_in[9];
    const int*   cols  = (const int*)d_in[10];

    float* out  = (float*)d_out;
    float* bank = out;                                  // bank lives in d_out
    float* crit_means = out + (size_t)(N_ + 1) * C_ * D_;

    const size_t NCD = (size_t)N_ * C_ * D_;
    float* ego   = (float*)d_ws;                        // (N,C,D) fp32
    float* buf   = ego + NCD;                           // gf / stacked (N,C,D)
    float* crit1 = buf + NCD;
    float* crit2 = crit1 + C_ * D_;
    int* bin_start = (int*)(crit2 + C_ * D_);           // BINS+1
    int* cnt       = bin_start + BINS_ + 1;             // BINS (hist, then cursor)
    int* blocksum  = cnt + BINS_;                       // 512
    int* perm      = blocksum + 512;                    // C*E
    size_t needed = ((char*)(perm + (size_t)C_ * E_)) - (char*)d_ws;
    bool use_csr = ws_size >= needed;

    init_kernel<<<(N_ * C_ * D_ / 4 + 255) / 256, 256, 0, stream>>>(user, item, bank, ego);
    crit_kernel<<<1, 128, 0, stream>>>(crit0, cl, crit1, crit2, crit_means);

    const int nbScan = (BINS_ + 1023) / 1024;           // 391
    if (use_csr) {
        hipMemsetAsync(cnt, 0, (size_t)BINS_ * sizeof(int), stream);
        hist_kernel<<<C_ * E_ / 256, 256, 0, stream>>>(rows, cnt);
        scanA_kernel<<<nbScan, 256, 0, stream>>>(cnt, bin_start, blocksum);
        scanB_kernel<<<1, 64, 0, stream>>>(blocksum, nbScan);
        scanC_kernel<<<nbScan, 256, 0, stream>>>(bin_start, blocksum);
        hipMemsetAsync(cnt, 0, (size_t)BINS_ * sizeof(int), stream);
        fill_kernel<<<C_ * E_ / 256, 256, 0, stream>>>(rows, bin_start, cnt, perm);
    }

    for (int l = 0; l < L_; ++l) {
        if (use_csr) {
            gather_kernel<<<BINS_ * 64 / 256, 256, 0, stream>>>(ego, vals, cols, bin_start, perm, buf);
        } else {
            hipMemsetAsync(buf, 0, NCD * sizeof(float), stream);
            scatter_kernel<<<(size_t)C_ * E_ * 32 / 256, 256, 0, stream>>>(ego, vals, rows, cols, buf);
        }
        rowgemm_kernel<<<256, 256, 0, stream>>>(buf, W, gl + (size_t)l * D_ * D_,
                                                l == 0 ? crit0 : crit1);
        attn_kernel<<<1024, 256, 0, stream>>>(buf, p1, p2, ego, bank, l == L_ - 1 ? 1 : 0);
    }
}

// Round 3
// 4263.699 us; speedup vs baseline: 6.3475x; 1.7516x over previous
//
#include <hip/hip_runtime.h>
#include <cstdint>
#include <cmath>

#define U_ 40000
#define I_ 40000
#define C_ 5
#define D_ 128
#define A_ 64
#define L_ 2
#define E_ 1280000
#define N_ (U_ + I_)
#define BINS_ (N_ * C_)

typedef __attribute__((ext_vector_type(8))) short short8;
typedef __attribute__((ext_vector_type(4))) float f32x4;

static __device__ __forceinline__ short f2bf(float f) {
    union { float f; uint32_t u; } x; x.f = f;
    uint32_t u = x.u;
    uint32_t r = (u + 0x7fffu + ((u >> 16) & 1u)) >> 16;   // RNE
    return (short)r;
}

// ---------------------------------------------------------------------------
// init: bank (=d_out[0..N*C*D)) = ego = concat(user, item); zero pad row
// ---------------------------------------------------------------------------
__global__ __launch_bounds__(256) void init_kernel(
    const float* __restrict__ user, const float* __restrict__ item,
    float* __restrict__ bank, float* __restrict__ ego)
{
    size_t i = (size_t)blockIdx.x * 256 + threadIdx.x;   // float4 index
    const size_t total4 = (size_t)N_ * C_ * D_ / 4;
    const size_t user4  = (size_t)U_ * C_ * D_ / 4;
    if (i < total4) {
        float4 v = (i < user4) ? ((const float4*)user)[i]
                               : ((const float4*)item)[i - user4];
        ((float4*)bank)[i] = v;
        ((float4*)ego)[i]  = v;
    }
    if (blockIdx.x == 0 && threadIdx.x < C_ * D_ / 4) {
        ((float4*)bank)[total4 + threadIdx.x] = make_float4(0.f, 0.f, 0.f, 0.f);
    }
}

// ---------------------------------------------------------------------------
// crit chain
// ---------------------------------------------------------------------------
__global__ __launch_bounds__(128) void crit_kernel(
    const float* __restrict__ crit0, const float* __restrict__ clayers,
    float* __restrict__ crit1, float* __restrict__ crit2,
    float* __restrict__ crit_means)
{
    __shared__ float c0[C_ * D_], c1[C_ * D_], c2[C_ * D_];
    int t = threadIdx.x;
    for (int i = t; i < C_ * D_; i += 128) c0[i] = crit0[i];
    __syncthreads();
    for (int c = 0; c < C_; ++c) {
        float acc = 0.f;
        for (int d = 0; d < D_; ++d) acc = fmaf(c0[c * D_ + d], clayers[d * D_ + t], acc);
        c1[c * D_ + t] = acc;
    }
    __syncthreads();
    for (int c = 0; c < C_; ++c) {
        float acc = 0.f;
        for (int d = 0; d < D_; ++d) acc = fmaf(c1[c * D_ + d], clayers[D_ * D_ + d * D_ + t], acc);
        c2[c * D_ + t] = acc;
    }
    __syncthreads();
    for (int i = t; i < C_ * D_; i += 128) {
        crit1[i] = c1[i];
        crit2[i] = c2[i];
        crit_means[i] = (c0[i] + c1[i] + c2[i]) * (1.0f / 3.0f);
    }
}

// ---------------------------------------------------------------------------
// prepack W / G0 / G1 into bf16 B-fragment layout for mfma_f32_16x16x32_bf16:
// frag[t][q][lane][j] = M[q*32 + (lane>>4)*8 + j][t*16 + (lane&15)]
// ---------------------------------------------------------------------------
__global__ __launch_bounds__(256) void prepack_kernel(
    const float* __restrict__ W, const float* __restrict__ gl,
    short* __restrict__ Wf, short* __restrict__ Gf)
{
    int b = blockIdx.x;               // 0..23: matrix = b>>3, t = b&7
    int m = b >> 3, t = b & 7;
    int q = threadIdx.x >> 6, l = threadIdx.x & 63;
    int g = l >> 4, c15 = l & 15;
    const float* src = (m == 0) ? W : gl + (size_t)(m - 1) * D_ * D_;
    short*       dst = (m == 0) ? Wf : Gf + (size_t)(m - 1) * D_ * D_;
    short8 v;
    #pragma unroll
    for (int j = 0; j < 8; ++j) {
        int k = q * 32 + g * 8 + j;
        int n = t * 16 + c15;
        v[j] = f2bf(src[k * D_ + n]);
    }
    *(short8*)(dst + (((t * 4 + q) * 64 + l) << 3)) = v;
}

// ---------------------------------------------------------------------------
// CSR build
// ---------------------------------------------------------------------------
__global__ __launch_bounds__(256) void hist_kernel(
    const int* __restrict__ rows, int* __restrict__ cnt)
{
    int eid = blockIdx.x * 256 + threadIdx.x;
    int c = eid / E_;
    int bin = rows[eid] * C_ + c;
    atomicAdd(&cnt[bin], 1);
}

__global__ __launch_bounds__(256) void scanA_kernel(
    const int* __restrict__ cnt, int* __restrict__ bin_start,
    int* __restrict__ blocksum)
{
    __shared__ int lsum[256];
    int b = blockIdx.x, t = threadIdx.x;
    int base = b * 1024 + t * 4;
    int v[4];
    #pragma unroll
    for (int i = 0; i < 4; ++i) v[i] = (base + i < BINS_) ? cnt[base + i] : 0;
    int s = v[0] + v[1] + v[2] + v[3];
    lsum[t] = s;
    __syncthreads();
    for (int off = 1; off < 256; off <<= 1) {
        int x = (t >= off) ? lsum[t - off] : 0;
        __syncthreads();
        lsum[t] += x;
        __syncthreads();
    }
    int excl = lsum[t] - s;
    if (t == 255) blocksum[b] = lsum[255];
    #pragma unroll
    for (int i = 0; i < 4; ++i) {
        if (base + i < BINS_) bin_start[base + i] = excl;
        excl += v[i];
    }
}

__global__ void scanB_kernel(int* __restrict__ blocksum, int nb)
{
    if (threadIdx.x == 0 && blockIdx.x == 0) {
        int acc = 0;
        for (int b = 0; b < nb; ++b) { int v = blocksum[b]; blocksum[b] = acc; acc += v; }
    }
}

__global__ __launch_bounds__(256) void scanC_kernel(
    int* __restrict__ bin_start, const int* __restrict__ blocksum)
{
    int b = blockIdx.x, t = threadIdx.x;
    int off = blocksum[b];
    int base = b * 1024 + t * 4;
    #pragma unroll
    for (int i = 0; i < 4; ++i)
        if (base + i < BINS_) bin_start[base + i] += off;
    if (b == 0 && t == 0) bin_start[BINS_] = C_ * E_;
}

__global__ __launch_bounds__(256) void fill_kernel(
    const int* __restrict__ rows, const int* __restrict__ bin_start,
    int* __restrict__ cursor, int* __restrict__ perm)
{
    int eid = blockIdx.x * 256 + threadIdx.x;
    int c = eid / E_;
    int bin = rows[eid] * C_ + c;
    int pos = bin_start[bin] + atomicAdd(&cursor[bin], 1);
    perm[pos] = eid;
}

// ---------------------------------------------------------------------------
// gather: one wave per dest bin
// ---------------------------------------------------------------------------
__global__ __launch_bounds__(256) void gather_kernel(
    const float* __restrict__ ego, const float* __restrict__ vals,
    const int* __restrict__ cols, const int* __restrict__ bin_start,
    const int* __restrict__ perm, float* __restrict__ gf)
{
    int w = (int)(((size_t)blockIdx.x * 256 + threadIdx.x) >> 6);
    int lane = threadIdx.x & 63;
    w = __builtin_amdgcn_readfirstlane(w);
    int bs = bin_start[w], be = bin_start[w + 1];
    int c = w % C_;
    float2 acc = make_float2(0.f, 0.f);
    int i = bs;
    for (; i + 1 < be; i += 2) {
        int e0 = perm[i], e1 = perm[i + 1];
        float v0 = vals[e0], v1 = vals[e1];
        int s0 = cols[e0], s1 = cols[e1];
        const float2* p0 = (const float2*)(ego + ((size_t)s0 * C_ + c) * D_);
        const float2* p1 = (const float2*)(ego + ((size_t)s1 * C_ + c) * D_);
        float2 m0 = p0[lane], m1 = p1[lane];
        acc.x = fmaf(v0, m0.x, acc.x); acc.y = fmaf(v0, m0.y, acc.y);
        acc.x = fmaf(v1, m1.x, acc.x); acc.y = fmaf(v1, m1.y, acc.y);
    }
    if (i < be) {
        int e0 = perm[i];
        float v0 = vals[e0]; int s0 = cols[e0];
        const float2* p0 = (const float2*)(ego + ((size_t)s0 * C_ + c) * D_);
        float2 m0 = p0[lane];
        acc.x = fmaf(v0, m0.x, acc.x); acc.y = fmaf(v0, m0.y, acc.y);
    }
    ((float2*)(gf + (size_t)w * D_))[lane] = acc;
}

// ---------------------------------------------------------------------------
// fallback scatter
// ---------------------------------------------------------------------------
__global__ __launch_bounds__(256) void scatter_kernel(
    const float* __restrict__ ego, const float* __restrict__ vals,
    const int* __restrict__ rows, const int* __restrict__ cols,
    float* __restrict__ gf)
{
    size_t gt = (size_t)blockIdx.x * 256 + threadIdx.x;
    uint32_t eid = (uint32_t)(gt >> 5);
    int lane = (int)(gt & 31);
    uint32_t c = eid / (uint32_t)E_;
    float v  = vals[eid];
    int  src = cols[eid];
    int  dst = rows[eid];
    const float4* sp = (const float4*)(ego + ((size_t)src * C_ + c) * D_);
    float4 m = sp[lane];
    float* dp = gf + ((size_t)dst * C_ + c) * D_ + lane * 4;
    atomicAdd(dp + 0, v * m.x);
    atomicAdd(dp + 1, v * m.y);
    atomicAdd(dp + 2, v * m.z);
    atomicAdd(dp + 3, v * m.w);
}

// ---------------------------------------------------------------------------
// rowgemm via MFMA: S = leaky((X@W * crit[row%5]) @ G), in-place on buf.
// 512 threads = 8 waves; wave = 16 rows; block = 128 rows; 3125 blocks.
// W staged in LDS (bf16 frags), same buffer restaged with G for GEMM2.
// Z transposed D-layout -> A-frag-layout through XOR-swizzled per-wave LDS.
// ---------------------------------------------------------------------------
__global__ __launch_bounds__(512, 4) void rowgemm_mfma_kernel(
    float* buf, const short* __restrict__ Wf, const short* __restrict__ Gf,
    const float* __restrict__ critv)
{
    __shared__ short WGl[16384];        // W frags, then reused for G frags
    __shared__ float critl[C_ * D_];
    __shared__ short Zr[8 * 2048];      // per-wave 16x128 bf16, XOR-swizzled

    for (int i = threadIdx.x; i < 2048; i += 512)
        ((short8*)WGl)[i] = ((const short8*)Wf)[i];
    for (int i = threadIdx.x; i < C_ * D_; i += 512) critl[i] = critv[i];
    __syncthreads();

    int lane = threadIdx.x & 63, w = threadIdx.x >> 6;
    int g = lane >> 4, c15 = lane & 15;
    size_t r0 = (size_t)blockIdx.x * 128 + (size_t)w * 16;

    // ---- A fragments of X (fp32 -> bf16 on the fly) ----
    short8 af[4];
    #pragma unroll
    for (int q = 0; q < 4; ++q) {
        const float* xp = buf + (r0 + c15) * D_ + q * 32 + g * 8;
        float4 x0 = *(const float4*)xp;
        float4 x1 = *(const float4*)(xp + 4);
        short8 a;
        a[0] = f2bf(x0.x); a[1] = f2bf(x0.y); a[2] = f2bf(x0.z); a[3] = f2bf(x0.w);
        a[4] = f2bf(x1.x); a[5] = f2bf(x1.y); a[6] = f2bf(x1.z); a[7] = f2bf(x1.w);
        af[q] = a;
    }

    // ---- GEMM1: Y = X @ W ----
    f32x4 acc[8];
    #pragma unroll
    for (int t = 0; t < 8; ++t) acc[t] = (f32x4){0.f, 0.f, 0.f, 0.f};
    {
        const short8* Wp = (const short8*)WGl;
        #pragma unroll
        for (int t = 0; t < 8; ++t)
            #pragma unroll
            for (int q = 0; q < 4; ++q)
                acc[t] = __builtin_amdgcn_mfma_f32_16x16x32_bf16(
                    af[q], Wp[(t * 4 + q) * 64 + lane], acc[t], 0, 0, 0);
    }

    // ---- scale by crit[row%5][col], write Z to swizzled LDS ----
    int rb = (int)r0 + g * 4;
    int cid[4];
    #pragma unroll
    for (int r = 0; r < 4; ++r) cid[r] = (rb + r) % C_;
    char* zw = (char*)&Zr[w * 2048];
    #pragma unroll
    for (int t = 0; t < 8; ++t)
        #pragma unroll
        for (int r = 0; r < 4; ++r) {
            float cv = critl[cid[r] * D_ + t * 16 + c15];
            float z = acc[t][r] * cv;
            int zrow = g * 4 + r;
            int cb = 32 * t + 2 * c15;
            int off = zrow * 256 + (cb ^ ((zrow & 7) << 4));
            *(short*)(zw + off) = f2bf(z);
        }
    __syncthreads();

    // ---- restage LDS with G fragments ----
    for (int i = threadIdx.x; i < 2048; i += 512)
        ((short8*)WGl)[i] = ((const short8*)Gf)[i];
    __syncthreads();

    // ---- A fragments of Z from swizzled LDS ----
    short8 az[4];
    #pragma unroll
    for (int q = 0; q < 4; ++q) {
        int cb0 = 64 * q + 16 * g;
        int off = c15 * 256 + (cb0 ^ ((c15 & 7) << 4));
        az[q] = *(const short8*)(zw + off);
    }

    // ---- GEMM2: S = Z @ G ----
    f32x4 acc2[8];
    #pragma unroll
    for (int t = 0; t < 8; ++t) acc2[t] = (f32x4){0.f, 0.f, 0.f, 0.f};
    {
        const short8* Gp = (const short8*)WGl;
        #pragma unroll
        for (int t = 0; t < 8; ++t)
            #pragma unroll
            for (int q = 0; q < 4; ++q)
                acc2[t] = __builtin_amdgcn_mfma_f32_16x16x32_bf16(
                    az[q], Gp[(t * 4 + q) * 64 + lane], acc2[t], 0, 0, 0);
    }

    // ---- leaky ReLU + store ----
    #pragma unroll
    for (int t = 0; t < 8; ++t)
        #pragma unroll
        for (int r = 0; r < 4; ++r) {
            float s = acc2[t][r];
            s = s > 0.f ? s : 0.01f * s;
            buf[(r0 + (size_t)(g * 4 + r)) * D_ + t * 16 + c15] = s;
        }
}

// ---------------------------------------------------------------------------
// attention
// ---------------------------------------------------------------------------
__global__ __launch_bounds__(256) void attn_kernel(
    const float* __restrict__ stacked, const float* __restrict__ p1,
    const float* __restrict__ p2, float* __restrict__ ego,
    float* __restrict__ bank, int last)
{
    __shared__ float sst[4][C_][D_];
    int wave = threadIdx.x >> 6, lane = threadIdx.x & 63;
    int gw = blockIdx.x * 4 + wave, nw = gridDim.x * 4;
    int iters = (N_ + nw - 1) / nw;
    for (int it = 0; it < iters; ++it) {
        int n = gw + it * nw;
        bool act = n < N_;
        for (int c = 0; c < C_; ++c) {
            float t0 = 0.f, t1 = 0.f;
            if (act) {
                t0 = stacked[((size_t)n * C_ + c) * D_ + lane];
                t1 = stacked[((size_t)n * C_ + c) * D_ + lane + 64];
            }
            sst[wave][c][lane] = t0;
            sst[wave][c][lane + 64] = t1;
        }
        __syncthreads();
        for (int k = 0; k < C_; ++k) {
            float acc[C_] = {0.f, 0.f, 0.f, 0.f, 0.f};
            const float* p1k = p1 + (size_t)k * D_ * A_;
            for (int d = 0; d < D_; d += 2) {
                float pv0 = p1k[(d + 0) * A_ + lane];
                float pv1 = p1k[(d + 1) * A_ + lane];
                #pragma unroll
                for (int c = 0; c < C_; ++c) {
                    float2 sv = *(const float2*)&sst[wave][c][d];
                    acc[c] = fmaf(sv.x, pv0, acc[c]);
                    acc[c] = fmaf(sv.y, pv1, acc[c]);
                }
            }
            float raw[C_];
            float pw = p2[k * A_ + lane];
            #pragma unroll
            for (int c = 0; c < C_; ++c) {
                float pr = tanhf(acc[c]) * pw;
                #pragma unroll
                for (int off = 32; off; off >>= 1) pr += __shfl_xor(pr, off);
                raw[c] = pr;
            }
            float m = raw[0];
            #pragma unroll
            for (int c = 1; c < C_; ++c) m = fmaxf(m, raw[c]);
            float s = 0.f, wgt[C_];
            #pragma unroll
            for (int c = 0; c < C_; ++c) { wgt[c] = __expf(raw[c] - m); s += wgt[c]; }
            float inv = 1.0f / s;
            float e0 = 0.f, e1 = 0.f;
            #pragma unroll
            for (int c = 0; c < C_; ++c) {
                float wc = wgt[c] * inv;
                e0 = fmaf(wc, sst[wave][c][lane], e0);
                e1 = fmaf(wc, sst[wave][c][lane + 64], e1);
            }
            if (act) {
                size_t o = ((size_t)n * C_ + k) * D_ + lane;
                ego[o] = e0; ego[o + 64] = e1;
                float b0 = bank[o] + e0, b1 = bank[o + 64] + e1;
                if (last) { b0 *= (1.0f / 3.0f); b1 *= (1.0f / 3.0f); }
                bank[o] = b0; bank[o + 64] = b1;
            }
        }
        __syncthreads();
    }
}

extern "C" void kernel_launch(void* const* d_in, const int* in_sizes, int n_in,
                              void* d_out, int out_size, void* d_ws, size_t ws_size,
                              hipStream_t stream) {
    const float* user  = (const float*)d_in[0];
    const float* item  = (const float*)d_in[1];
    const float* crit0 = (const float*)d_in[2];
    const float* W     = (const float*)d_in[3];
    const float* gl    = (const float*)d_in[4];
    const float* cl    = (const float*)d_in[5];
    const float* p1    = (const float*)d_in[6];
    const float* p2    = (const float*)d_in[7];
    const float* vals  = (const float*)d_in[8];
    const int*   rows  = (const int*)d_in[9];
    const int*   cols  = (const int*)d_in[10];

    float* out  = (float*)d_out;
    float* bank = out;
    float* crit_means = out + (size_t)(N_ + 1) * C_ * D_;

    const size_t NCD = (size_t)N_ * C_ * D_;
    float* ego   = (float*)d_ws;
    float* buf   = ego + NCD;
    float* crit1 = buf + NCD;
    float* crit2 = crit1 + C_ * D_;
    short* Wf    = (short*)(crit2 + C_ * D_);           // 16384 bf16
    short* Gf    = Wf + (size_t)D_ * D_;                // 2 x 16384 bf16
    int* bin_start = (int*)(Gf + 2 * (size_t)D_ * D_);  // BINS+1
    int* cnt       = bin_start + BINS_ + 1;
    int* blocksum  = cnt + BINS_;
    int* perm      = blocksum + 512;
    size_t needed = ((char*)(perm + (size_t)C_ * E_)) - (char*)d_ws;
    bool use_csr = ws_size >= needed;

    init_kernel<<<(N_ * C_ * D_ / 4 + 255) / 256, 256, 0, stream>>>(user, item, bank, ego);
    crit_kernel<<<1, 128, 0, stream>>>(crit0, cl, crit1, crit2, crit_means);
    prepack_kernel<<<24, 256, 0, stream>>>(W, gl, Wf, Gf);

    const int nbScan = (BINS_ + 1023) / 1024;
    if (use_csr) {
        hipMemsetAsync(cnt, 0, (size_t)BINS_ * sizeof(int), stream);
        hist_kernel<<<C_ * E_ / 256, 256, 0, stream>>>(rows, cnt);
        scanA_kernel<<<nbScan, 256, 0, stream>>>(cnt, bin_start, blocksum);
        scanB_kernel<<<1, 64, 0, stream>>>(blocksum, nbScan);
        scanC_kernel<<<nbScan, 256, 0, stream>>>(bin_start, blocksum);
        hipMemsetAsync(cnt, 0, (size_t)BINS_ * sizeof(int), stream);
        fill_kernel<<<C_ * E_ / 256, 256, 0, stream>>>(rows, bin_start, cnt, perm);
    }

    for (int l = 0; l < L_; ++l) {
        if (use_csr) {
            gather_kernel<<<BINS_ * 64 / 256, 256, 0, stream>>>(ego, vals, cols, bin_start, perm, buf);
        } else {
            hipMemsetAsync(buf, 0, NCD * sizeof(float), stream);
            scatter_kernel<<<(size_t)C_ * E_ * 32 / 256, 256, 0, stream>>>(ego, vals, rows, cols, buf);
        }
        rowgemm_mfma_kernel<<<N_ * C_ / 128, 512, 0, stream>>>(
            buf, Wf, Gf + (size_t)l * D_ * D_, l == 0 ? crit0 : crit1);
        attn_kernel<<<1024, 256, 0, stream>>>(buf, p1, p2, ego, bank, l == L_ - 1 ? 1 : 0);
    }
}

// Round 4
// 2821.897 us; speedup vs baseline: 9.5906x; 1.5109x over previous
//
#include <hip/hip_runtime.h>
#include <cstdint>
#include <cmath>

#define U_ 40000
#define I_ 40000
#define C_ 5
#define D_ 128
#define A_ 64
#define L_ 2
#define E_ 1280000
#define N_ (U_ + I_)
#define BINS_ (N_ * C_)

typedef __attribute__((ext_vector_type(8))) short short8;
typedef __attribute__((ext_vector_type(4))) float f32x4;

static __device__ __forceinline__ short f2bf(float f) {
    union { float f; uint32_t u; } x; x.f = f;
    uint32_t u = x.u;
    uint32_t r = (u + 0x7fffu + ((u >> 16) & 1u)) >> 16;   // RNE
    return (short)r;
}

// ---------------------------------------------------------------------------
// init: bank (=d_out[0..N*C*D)) = ego = concat(user, item); zero pad row
// ---------------------------------------------------------------------------
__global__ __launch_bounds__(256) void init_kernel(
    const float* __restrict__ user, const float* __restrict__ item,
    float* __restrict__ bank, float* __restrict__ ego)
{
    size_t i = (size_t)blockIdx.x * 256 + threadIdx.x;   // float4 index
    const size_t total4 = (size_t)N_ * C_ * D_ / 4;
    const size_t user4  = (size_t)U_ * C_ * D_ / 4;
    if (i < total4) {
        float4 v = (i < user4) ? ((const float4*)user)[i]
                               : ((const float4*)item)[i - user4];
        ((float4*)bank)[i] = v;
        ((float4*)ego)[i]  = v;
    }
    if (blockIdx.x == 0 && threadIdx.x < C_ * D_ / 4) {
        ((float4*)bank)[total4 + threadIdx.x] = make_float4(0.f, 0.f, 0.f, 0.f);
    }
}

// ---------------------------------------------------------------------------
// crit chain
// ---------------------------------------------------------------------------
__global__ __launch_bounds__(128) void crit_kernel(
    const float* __restrict__ crit0, const float* __restrict__ clayers,
    float* __restrict__ crit1, float* __restrict__ crit2,
    float* __restrict__ crit_means)
{
    __shared__ float c0[C_ * D_], c1[C_ * D_], c2[C_ * D_];
    int t = threadIdx.x;
    for (int i = t; i < C_ * D_; i += 128) c0[i] = crit0[i];
    __syncthreads();
    for (int c = 0; c < C_; ++c) {
        float acc = 0.f;
        for (int d = 0; d < D_; ++d) acc = fmaf(c0[c * D_ + d], clayers[d * D_ + t], acc);
        c1[c * D_ + t] = acc;
    }
    __syncthreads();
    for (int c = 0; c < C_; ++c) {
        float acc = 0.f;
        for (int d = 0; d < D_; ++d) acc = fmaf(c1[c * D_ + d], clayers[D_ * D_ + d * D_ + t], acc);
        c2[c * D_ + t] = acc;
    }
    __syncthreads();
    for (int i = t; i < C_ * D_; i += 128) {
        crit1[i] = c1[i];
        crit2[i] = c2[i];
        crit_means[i] = (c0[i] + c1[i] + c2[i]) * (1.0f / 3.0f);
    }
}

// ---------------------------------------------------------------------------
// prepack W / G0 / G1 into bf16 B-fragment layout for mfma_f32_16x16x32_bf16:
// frag[t][q][lane][j] = M[q*32 + (lane>>4)*8 + j][t*16 + (lane&15)]
// ---------------------------------------------------------------------------
__global__ __launch_bounds__(256) void prepack_kernel(
    const float* __restrict__ W, const float* __restrict__ gl,
    short* __restrict__ Wf, short* __restrict__ Gf)
{
    int b = blockIdx.x;               // 0..23: matrix = b>>3, t = b&7
    int m = b >> 3, t = b & 7;
    int q = threadIdx.x >> 6, l = threadIdx.x & 63;
    int g = l >> 4, c15 = l & 15;
    const float* src = (m == 0) ? W : gl + (size_t)(m - 1) * D_ * D_;
    short*       dst = (m == 0) ? Wf : Gf + (size_t)(m - 1) * D_ * D_;
    short8 v;
    #pragma unroll
    for (int j = 0; j < 8; ++j) {
        int k = q * 32 + g * 8 + j;
        int n = t * 16 + c15;
        v[j] = f2bf(src[k * D_ + n]);
    }
    *(short8*)(dst + (((t * 4 + q) * 64 + l) << 3)) = v;
}

// ---------------------------------------------------------------------------
// prepack p1 (C,D,A) as B-frags of P1all (128 x 320), col = k*64 + a
// ---------------------------------------------------------------------------
__global__ __launch_bounds__(64) void prepack_p1_kernel(
    const float* __restrict__ p1, short* __restrict__ P1f)
{
    int t = blockIdx.x >> 2, q = blockIdx.x & 3;   // 80 blocks: t 0..19
    int lane = threadIdx.x;
    int g = lane >> 4, c15 = lane & 15;
    int k = t >> 2, a = (t & 3) * 16 + c15;
    short8 v;
    #pragma unroll
    for (int j = 0; j < 8; ++j) {
        int d = q * 32 + g * 8 + j;
        v[j] = f2bf(p1[((size_t)k * D_ + d) * A_ + a]);
    }
    *(short8*)(P1f + (((t * 4 + q) * 64 + lane) << 3)) = v;
}

// ---------------------------------------------------------------------------
// CSR build
// ---------------------------------------------------------------------------
__global__ __launch_bounds__(256) void hist_kernel(
    const int* __restrict__ rows, int* __restrict__ cnt)
{
    int eid = blockIdx.x * 256 + threadIdx.x;
    int c = eid / E_;
    int bin = rows[eid] * C_ + c;
    atomicAdd(&cnt[bin], 1);
}

__global__ __launch_bounds__(256) void scanA_kernel(
    const int* __restrict__ cnt, int* __restrict__ bin_start,
    int* __restrict__ blocksum)
{
    __shared__ int lsum[256];
    int b = blockIdx.x, t = threadIdx.x;
    int base = b * 1024 + t * 4;
    int v[4];
    #pragma unroll
    for (int i = 0; i < 4; ++i) v[i] = (base + i < BINS_) ? cnt[base + i] : 0;
    int s = v[0] + v[1] + v[2] + v[3];
    lsum[t] = s;
    __syncthreads();
    for (int off = 1; off < 256; off <<= 1) {
        int x = (t >= off) ? lsum[t - off] : 0;
        __syncthreads();
        lsum[t] += x;
        __syncthreads();
    }
    int excl = lsum[t] - s;
    if (t == 255) blocksum[b] = lsum[255];
    #pragma unroll
    for (int i = 0; i < 4; ++i) {
        if (base + i < BINS_) bin_start[base + i] = excl;
        excl += v[i];
    }
}

__global__ void scanB_kernel(int* __restrict__ blocksum, int nb)
{
    if (threadIdx.x == 0 && blockIdx.x == 0) {
        int acc = 0;
        for (int b = 0; b < nb; ++b) { int v = blocksum[b]; blocksum[b] = acc; acc += v; }
    }
}

__global__ __launch_bounds__(256) void scanC_kernel(
    int* __restrict__ bin_start, const int* __restrict__ blocksum)
{
    int b = blockIdx.x, t = threadIdx.x;
    int off = blocksum[b];
    int base = b * 1024 + t * 4;
    #pragma unroll
    for (int i = 0; i < 4; ++i)
        if (base + i < BINS_) bin_start[base + i] += off;
    if (b == 0 && t == 0) bin_start[BINS_] = C_ * E_;
}

__global__ __launch_bounds__(256) void fill_kernel(
    const int* __restrict__ rows, const int* __restrict__ bin_start,
    int* __restrict__ cursor, int* __restrict__ perm)
{
    int eid = blockIdx.x * 256 + threadIdx.x;
    int c = eid / E_;
    int bin = rows[eid] * C_ + c;
    int pos = bin_start[bin] + atomicAdd(&cursor[bin], 1);
    perm[pos] = eid;
}

// ---------------------------------------------------------------------------
// gather: one wave per dest bin
// ---------------------------------------------------------------------------
__global__ __launch_bounds__(256) void gather_kernel(
    const float* __restrict__ ego, const float* __restrict__ vals,
    const int* __restrict__ cols, const int* __restrict__ bin_start,
    const int* __restrict__ perm, float* __restrict__ gf)
{
    int w = (int)(((size_t)blockIdx.x * 256 + threadIdx.x) >> 6);
    int lane = threadIdx.x & 63;
    w = __builtin_amdgcn_readfirstlane(w);
    int bs = bin_start[w], be = bin_start[w + 1];
    int c = w % C_;
    float2 acc = make_float2(0.f, 0.f);
    int i = bs;
    for (; i + 1 < be; i += 2) {
        int e0 = perm[i], e1 = perm[i + 1];
        float v0 = vals[e0], v1 = vals[e1];
        int s0 = cols[e0], s1 = cols[e1];
        const float2* p0 = (const float2*)(ego + ((size_t)s0 * C_ + c) * D_);
        const float2* p1 = (const float2*)(ego + ((size_t)s1 * C_ + c) * D_);
        float2 m0 = p0[lane], m1 = p1[lane];
        acc.x = fmaf(v0, m0.x, acc.x); acc.y = fmaf(v0, m0.y, acc.y);
        acc.x = fmaf(v1, m1.x, acc.x); acc.y = fmaf(v1, m1.y, acc.y);
    }
    if (i < be) {
        int e0 = perm[i];
        float v0 = vals[e0]; int s0 = cols[e0];
        const float2* p0 = (const float2*)(ego + ((size_t)s0 * C_ + c) * D_);
        float2 m0 = p0[lane];
        acc.x = fmaf(v0, m0.x, acc.x); acc.y = fmaf(v0, m0.y, acc.y);
    }
    ((float2*)(gf + (size_t)w * D_))[lane] = acc;
}

// ---------------------------------------------------------------------------
// rowgemm via MFMA: S = leaky((X@W * crit[row%5]) @ G), in-place on buf.
// ---------------------------------------------------------------------------
__global__ __launch_bounds__(512, 4) void rowgemm_mfma_kernel(
    float* buf, const short* __restrict__ Wf, const short* __restrict__ Gf,
    const float* __restrict__ critv)
{
    __shared__ short WGl[16384];        // W frags, then reused for G frags
    __shared__ float critl[C_ * D_];
    __shared__ short Zr[8 * 2048];      // per-wave 16x128 bf16, XOR-swizzled

    for (int i = threadIdx.x; i < 2048; i += 512)
        ((short8*)WGl)[i] = ((const short8*)Wf)[i];
    for (int i = threadIdx.x; i < C_ * D_; i += 512) critl[i] = critv[i];
    __syncthreads();

    int lane = threadIdx.x & 63, w = threadIdx.x >> 6;
    int g = lane >> 4, c15 = lane & 15;
    size_t r0 = (size_t)blockIdx.x * 128 + (size_t)w * 16;

    short8 af[4];
    #pragma unroll
    for (int q = 0; q < 4; ++q) {
        const float* xp = buf + (r0 + c15) * D_ + q * 32 + g * 8;
        float4 x0 = *(const float4*)xp;
        float4 x1 = *(const float4*)(xp + 4);
        short8 a;
        a[0] = f2bf(x0.x); a[1] = f2bf(x0.y); a[2] = f2bf(x0.z); a[3] = f2bf(x0.w);
        a[4] = f2bf(x1.x); a[5] = f2bf(x1.y); a[6] = f2bf(x1.z); a[7] = f2bf(x1.w);
        af[q] = a;
    }

    f32x4 acc[8];
    #pragma unroll
    for (int t = 0; t < 8; ++t) acc[t] = (f32x4){0.f, 0.f, 0.f, 0.f};
    {
        const short8* Wp = (const short8*)WGl;
        #pragma unroll
        for (int t = 0; t < 8; ++t)
            #pragma unroll
            for (int q = 0; q < 4; ++q)
                acc[t] = __builtin_amdgcn_mfma_f32_16x16x32_bf16(
                    af[q], Wp[(t * 4 + q) * 64 + lane], acc[t], 0, 0, 0);
    }

    int rb = (int)r0 + g * 4;
    int cid[4];
    #pragma unroll
    for (int r = 0; r < 4; ++r) cid[r] = (rb + r) % C_;
    char* zw = (char*)&Zr[w * 2048];
    #pragma unroll
    for (int t = 0; t < 8; ++t)
        #pragma unroll
        for (int r = 0; r < 4; ++r) {
            float cv = critl[cid[r] * D_ + t * 16 + c15];
            float z = acc[t][r] * cv;
            int zrow = g * 4 + r;
            int cb = 32 * t + 2 * c15;
            int off = zrow * 256 + (cb ^ ((zrow & 7) << 4));
            *(short*)(zw + off) = f2bf(z);
        }
    __syncthreads();

    for (int i = threadIdx.x; i < 2048; i += 512)
        ((short8*)WGl)[i] = ((const short8*)Gf)[i];
    __syncthreads();

    short8 az[4];
    #pragma unroll
    for (int q = 0; q < 4; ++q) {
        int cb0 = 64 * q + 16 * g;
        int off = c15 * 256 + (cb0 ^ ((c15 & 7) << 4));
        az[q] = *(const short8*)(zw + off);
    }

    f32x4 acc2[8];
    #pragma unroll
    for (int t = 0; t < 8; ++t) acc2[t] = (f32x4){0.f, 0.f, 0.f, 0.f};
    {
        const short8* Gp = (const short8*)WGl;
        #pragma unroll
        for (int t = 0; t < 8; ++t)
            #pragma unroll
            for (int q = 0; q < 4; ++q)
                acc2[t] = __builtin_amdgcn_mfma_f32_16x16x32_bf16(
                    az[q], Gp[(t * 4 + q) * 64 + lane], acc2[t], 0, 0, 0);
    }

    #pragma unroll
    for (int t = 0; t < 8; ++t)
        #pragma unroll
        for (int r = 0; r < 4; ++r) {
            float s = acc2[t][r];
            s = s > 0.f ? s : 0.01f * s;
            buf[(r0 + (size_t)(g * 4 + r)) * D_ + t * 16 + c15] = s;
        }
}

// ---------------------------------------------------------------------------
// attention via MFMA: per group of 16 nodes (80 stacked rows):
//   H = stacked_tile(80x128) @ P1all(128x320)  [bf16 MFMA]
//   raw[row][k] = sum_a tanh(H)[row][k*64+a] * p2[k][a]
//   softmax over c; ego[n,k,:] = sum_c w * stacked[n,c,:]; bank += ego
// 4 waves; wave w owns col-tiles 5w..5w+4 (B-frags in registers, loaded once)
// ---------------------------------------------------------------------------
__global__ __launch_bounds__(256, 3) void attn_mfma_kernel(
    const float* __restrict__ buf, const short* __restrict__ P1f,
    const float* __restrict__ p2, float* __restrict__ ego,
    float* __restrict__ bank, int last)
{
    __shared__ float4 S4l[80][32];      // swizzled: [row][f4 ^ (row&7)]
    __shared__ float rawl[80 * C_];
    __shared__ float wl[80 * C_];

    int tid = threadIdx.x;
    int lane = tid & 63, w = tid >> 6;
    int g = lane >> 4, c15 = lane & 15;
    int klo = (5 * w) >> 2;             // wave's two k groups (klo, klo+1)

    // B-fragments (5 col-tiles x 4 ksteps) in registers, once per block
    short8 Bf[5][4];
    float p2v[5];
    #pragma unroll
    for (int i = 0; i < 5; ++i) {
        int t = 5 * w + i;
        #pragma unroll
        for (int q = 0; q < 4; ++q)
            Bf[i][q] = ((const short8*)P1f)[(t * 4 + q) * 64 + lane];
        p2v[i] = p2[(t >> 2) * A_ + (t & 3) * 16 + c15];
    }

    const float4* buf4  = (const float4*)buf;
    float4*       ego4  = (float4*)ego;
    float4*       bank4 = (float4*)bank;

    for (int grp = blockIdx.x; grp < N_ / 16; grp += gridDim.x) {
        size_t n0 = (size_t)grp * 16;
        __syncthreads();                 // previous iter's ego phase done
        // ---- stage S tile (80 rows x 32 float4), swizzled; zero rawl ----
        for (int idx = tid; idx < 2560; idx += 256) {
            int row = idx >> 5, f4 = idx & 31;
            S4l[row][f4 ^ (row & 7)] = buf4[(n0 * 5 + row) * 32 + f4];
        }
        for (int i = tid; i < 80 * C_; i += 256) rawl[i] = 0.f;
        __syncthreads();

        // ---- MFMA + tanh/p2 reduce per row-tile ----
        for (int rt = 0; rt < 5; ++rt) {
            short8 af[4];
            #pragma unroll
            for (int q = 0; q < 4; ++q) {
                int row = rt * 16 + c15;
                int f4a = 8 * q + 2 * g;
                float4 x0 = S4l[row][f4a ^ (row & 7)];
                float4 x1 = S4l[row][(f4a + 1) ^ (row & 7)];
                short8 a;
                a[0] = f2bf(x0.x); a[1] = f2bf(x0.y); a[2] = f2bf(x0.z); a[3] = f2bf(x0.w);
                a[4] = f2bf(x1.x); a[5] = f2bf(x1.y); a[6] = f2bf(x1.z); a[7] = f2bf(x1.w);
                af[q] = a;
            }
            f32x4 acc[5];
            #pragma unroll
            for (int i = 0; i < 5; ++i) acc[i] = (f32x4){0.f, 0.f, 0.f, 0.f};
            #pragma unroll
            for (int i = 0; i < 5; ++i)
                #pragma unroll
                for (int q = 0; q < 4; ++q)
                    acc[i] = __builtin_amdgcn_mfma_f32_16x16x32_bf16(
                        af[q], Bf[i][q], acc[i], 0, 0, 0);

            float2 ps[4];
            #pragma unroll
            for (int r = 0; r < 4; ++r) ps[r] = make_float2(0.f, 0.f);
            #pragma unroll
            for (int i = 0; i < 5; ++i) {
                int t = 5 * w + i;
                bool lo = (t >> 2) == klo;      // wave-uniform
                #pragma unroll
                for (int r = 0; r < 4; ++r) {
                    float x = acc[i][r];
                    float e = __expf(2.f * x);
                    float th = 1.f - 2.f * __builtin_amdgcn_rcpf(e + 1.f);
                    float con = th * p2v[i];
                    if (lo) ps[r].x += con; else ps[r].y += con;
                }
            }
            #pragma unroll
            for (int r = 0; r < 4; ++r) {
                #pragma unroll
                for (int m = 1; m < 16; m <<= 1) {
                    ps[r].x += __shfl_xor(ps[r].x, m);
                    ps[r].y += __shfl_xor(ps[r].y, m);
                }
                if (c15 == 0) {
                    int row = rt * 16 + g * 4 + r;
                    atomicAdd(&rawl[row * C_ + klo], ps[r].x);
                    atomicAdd(&rawl[row * C_ + klo + 1], ps[r].y);
                }
            }
        }
        __syncthreads();

        // ---- softmax over c for 16 nodes x 5 k ----
        if (tid < 80) {
            int nl = tid / C_, k = tid % C_;
            float rv[C_];
            #pragma unroll
            for (int c = 0; c < C_; ++c) rv[c] = rawl[(nl * C_ + c) * C_ + k];
            float m = rv[0];
            #pragma unroll
            for (int c = 1; c < C_; ++c) m = fmaxf(m, rv[c]);
            float s = 0.f;
            #pragma unroll
            for (int c = 0; c < C_; ++c) { rv[c] = __expf(rv[c] - m); s += rv[c]; }
            float inv = __builtin_amdgcn_rcpf(s);
            #pragma unroll
            for (int c = 0; c < C_; ++c) wl[tid * C_ + c] = rv[c] * inv;
        }
        __syncthreads();

        // ---- ego = sum_c w*S; bank += ego (last: /3) ----
        #pragma unroll
        for (int ii = 0; ii < 10; ++ii) {
            int idx = tid + 256 * ii;           // (k*16 + nl)*32 + f4
            int f4 = idx & 31, nk = idx >> 5;
            int nl = nk & 15, k = idx >> 9;
            float4 a = make_float4(0.f, 0.f, 0.f, 0.f);
            #pragma unroll
            for (int c = 0; c < C_; ++c) {
                float wv = wl[(nl * C_ + k) * C_ + c];
                int row = nl * C_ + c;
                float4 s = S4l[row][f4 ^ (row & 7)];
                a.x = fmaf(wv, s.x, a.x); a.y = fmaf(wv, s.y, a.y);
                a.z = fmaf(wv, s.z, a.z); a.w = fmaf(wv, s.w, a.w);
            }
            size_t go = ((n0 + nl) * 5 + k) * 32 + f4;
            float4 b = bank4[go];
            b.x += a.x; b.y += a.y; b.z += a.z; b.w += a.w;
            if (last) { b.x *= (1.f/3.f); b.y *= (1.f/3.f); b.z *= (1.f/3.f); b.w *= (1.f/3.f); }
            ego4[go] = a;
            bank4[go] = b;
        }
    }
}

extern "C" void kernel_launch(void* const* d_in, const int* in_sizes, int n_in,
                              void* d_out, int out_size, void* d_ws, size_t ws_size,
                              hipStream_t stream) {
    const float* user  = (const float*)d_in[0];
    const float* item  = (const float*)d_in[1];
    const float* crit0 = (const float*)d_in[2];
    const float* W     = (const float*)d_in[3];
    const float* gl    = (const float*)d_in[4];
    const float* cl    = (const float*)d_in[5];
    const float* p1    = (const float*)d_in[6];
    const float* p2    = (const float*)d_in[7];
    const float* vals  = (const float*)d_in[8];
    const int*   rows  = (const int*)d_in[9];
    const int*   cols  = (const int*)d_in[10];

    float* out  = (float*)d_out;
    float* bank = out;
    float* crit_means = out + (size_t)(N_ + 1) * C_ * D_;

    const size_t NCD = (size_t)N_ * C_ * D_;
    float* ego   = (float*)d_ws;
    float* buf   = ego + NCD;
    float* crit1 = buf + NCD;
    float* crit2 = crit1 + C_ * D_;
    short* Wf    = (short*)(crit2 + C_ * D_);           // 16384 bf16
    short* Gf    = Wf + (size_t)D_ * D_;                // 2 x 16384 bf16
    short* P1f   = Gf + 2 * (size_t)D_ * D_;            // 128*320 bf16
    int* bin_start = (int*)(P1f + (size_t)D_ * C_ * A_);
    int* cnt       = bin_start + BINS_ + 1;
    int* blocksum  = cnt + BINS_;
    int* perm      = blocksum + 512;
    size_t needed = ((char*)(perm + (size_t)C_ * E_)) - (char*)d_ws;
    bool use_csr = ws_size >= needed;

    init_kernel<<<(N_ * C_ * D_ / 4 + 255) / 256, 256, 0, stream>>>(user, item, bank, ego);
    crit_kernel<<<1, 128, 0, stream>>>(crit0, cl, crit1, crit2, crit_means);
    prepack_kernel<<<24, 256, 0, stream>>>(W, gl, Wf, Gf);
    prepack_p1_kernel<<<80, 64, 0, stream>>>(p1, P1f);

    const int nbScan = (BINS_ + 1023) / 1024;
    if (use_csr) {
        hipMemsetAsync(cnt, 0, (size_t)BINS_ * sizeof(int), stream);
        hist_kernel<<<C_ * E_ / 256, 256, 0, stream>>>(rows, cnt);
        scanA_kernel<<<nbScan, 256, 0, stream>>>(cnt, bin_start, blocksum);
        scanB_kernel<<<1, 64, 0, stream>>>(blocksum, nbScan);
        scanC_kernel<<<nbScan, 256, 0, stream>>>(bin_start, blocksum);
        hipMemsetAsync(cnt, 0, (size_t)BINS_ * sizeof(int), stream);
        fill_kernel<<<C_ * E_ / 256, 256, 0, stream>>>(rows, bin_start, cnt, perm);
    }

    for (int l = 0; l < L_; ++l) {
        if (use_csr) {
            gather_kernel<<<BINS_ * 64 / 256, 256, 0, stream>>>(ego, vals, cols, bin_start, perm, buf);
        } else {
            hipMemsetAsync(buf, 0, NCD * sizeof(float), stream);
        }
        rowgemm_mfma_kernel<<<N_ * C_ / 128, 512, 0, stream>>>(
            buf, Wf, Gf + (size_t)l * D_ * D_, l == 0 ? crit0 : crit1);
        attn_mfma_kernel<<<768, 256, 0, stream>>>(
            buf, P1f, p2, ego, bank, l == L_ - 1 ? 1 : 0);
    }
}

// Round 5
// 2210.618 us; speedup vs baseline: 12.2426x; 1.2765x over previous
//
#include <hip/hip_runtime.h>
#include <cstdint>
#include <cmath>

#define U_ 40000
#define I_ 40000
#define C_ 5
#define D_ 128
#define A_ 64
#define L_ 2
#define E_ 1280000
#define N_ (U_ + I_)
#define BINS_ (N_ * C_)

typedef __attribute__((ext_vector_type(8))) short short8;
typedef __attribute__((ext_vector_type(4))) short short4v;
typedef __attribute__((ext_vector_type(4))) float f32x4;

static __device__ __forceinline__ short f2bf(float f) {
    union { float f; uint32_t u; } x; x.f = f;
    uint32_t u = x.u;
    uint32_t r = (u + 0x7fffu + ((u >> 16) & 1u)) >> 16;   // RNE
    return (short)r;
}

// ---------------------------------------------------------------------------
// init: bank (=d_out) = concat(user,item) fp32; egob = same in bf16; pad row 0
// one thread = 8 floats
// ---------------------------------------------------------------------------
__global__ __launch_bounds__(256) void init_kernel(
    const float* __restrict__ user, const float* __restrict__ item,
    float* __restrict__ bank, short* __restrict__ egob)
{
    size_t i = (size_t)blockIdx.x * 256 + threadIdx.x;    // 8-float index
    const size_t total8 = (size_t)N_ * C_ * D_ / 8;
    const size_t user4  = (size_t)U_ * C_ * D_ / 4;
    if (i < total8) {
        size_t f4 = 2 * i;
        const float4* src = (f4 < user4) ? (const float4*)user
                                         : (const float4*)item - user4;
        float4 x0 = src[f4], x1 = src[f4 + 1];
        ((float4*)bank)[f4] = x0;
        ((float4*)bank)[f4 + 1] = x1;
        short8 p;
        p[0] = f2bf(x0.x); p[1] = f2bf(x0.y); p[2] = f2bf(x0.z); p[3] = f2bf(x0.w);
        p[4] = f2bf(x1.x); p[5] = f2bf(x1.y); p[6] = f2bf(x1.z); p[7] = f2bf(x1.w);
        ((short8*)egob)[i] = p;
    }
    if (blockIdx.x == 0 && threadIdx.x < C_ * D_ / 4) {
        ((float4*)bank)[(size_t)N_ * C_ * D_ / 4 + threadIdx.x] =
            make_float4(0.f, 0.f, 0.f, 0.f);
    }
}

// ---------------------------------------------------------------------------
// crit chain
// ---------------------------------------------------------------------------
__global__ __launch_bounds__(128) void crit_kernel(
    const float* __restrict__ crit0, const float* __restrict__ clayers,
    float* __restrict__ crit1, float* __restrict__ crit2,
    float* __restrict__ crit_means)
{
    __shared__ float c0[C_ * D_], c1[C_ * D_], c2[C_ * D_];
    int t = threadIdx.x;
    for (int i = t; i < C_ * D_; i += 128) c0[i] = crit0[i];
    __syncthreads();
    for (int c = 0; c < C_; ++c) {
        float acc = 0.f;
        for (int d = 0; d < D_; ++d) acc = fmaf(c0[c * D_ + d], clayers[d * D_ + t], acc);
        c1[c * D_ + t] = acc;
    }
    __syncthreads();
    for (int c = 0; c < C_; ++c) {
        float acc = 0.f;
        for (int d = 0; d < D_; ++d) acc = fmaf(c1[c * D_ + d], clayers[D_ * D_ + d * D_ + t], acc);
        c2[c * D_ + t] = acc;
    }
    __syncthreads();
    for (int i = t; i < C_ * D_; i += 128) {
        crit1[i] = c1[i];
        crit2[i] = c2[i];
        crit_means[i] = (c0[i] + c1[i] + c2[i]) * (1.0f / 3.0f);
    }
}

// ---------------------------------------------------------------------------
// prepack W / G0 / G1 into bf16 B-fragment layout (mfma_f32_16x16x32_bf16)
// ---------------------------------------------------------------------------
__global__ __launch_bounds__(256) void prepack_kernel(
    const float* __restrict__ W, const float* __restrict__ gl,
    short* __restrict__ Wf, short* __restrict__ Gf)
{
    int b = blockIdx.x;               // 0..23: matrix = b>>3, t = b&7
    int m = b >> 3, t = b & 7;
    int q = threadIdx.x >> 6, l = threadIdx.x & 63;
    int g = l >> 4, c15 = l & 15;
    const float* src = (m == 0) ? W : gl + (size_t)(m - 1) * D_ * D_;
    short*       dst = (m == 0) ? Wf : Gf + (size_t)(m - 1) * D_ * D_;
    short8 v;
    #pragma unroll
    for (int j = 0; j < 8; ++j) {
        int k = q * 32 + g * 8 + j;
        int n = t * 16 + c15;
        v[j] = f2bf(src[k * D_ + n]);
    }
    *(short8*)(dst + (((t * 4 + q) * 64 + l) << 3)) = v;
}

// ---------------------------------------------------------------------------
// prepack p1 (C,D,A) as B-frags of P1all (128 x 320)
// ---------------------------------------------------------------------------
__global__ __launch_bounds__(64) void prepack_p1_kernel(
    const float* __restrict__ p1, short* __restrict__ P1f)
{
    int t = blockIdx.x >> 2, q = blockIdx.x & 3;   // 80 blocks
    int lane = threadIdx.x;
    int g = lane >> 4, c15 = lane & 15;
    int k = t >> 2, a = (t & 3) * 16 + c15;
    short8 v;
    #pragma unroll
    for (int j = 0; j < 8; ++j) {
        int d = q * 32 + g * 8 + j;
        v[j] = f2bf(p1[((size_t)k * D_ + d) * A_ + a]);
    }
    *(short8*)(P1f + (((t * 4 + q) * 64 + lane) << 3)) = v;
}

// ---------------------------------------------------------------------------
// CSR build
// ---------------------------------------------------------------------------
__global__ __launch_bounds__(256) void hist_kernel(
    const int* __restrict__ rows, int* __restrict__ cnt)
{
    int eid = blockIdx.x * 256 + threadIdx.x;
    int c = eid / E_;
    int bin = rows[eid] * C_ + c;
    atomicAdd(&cnt[bin], 1);
}

__global__ __launch_bounds__(256) void scanA_kernel(
    const int* __restrict__ cnt, int* __restrict__ bin_start,
    int* __restrict__ blocksum)
{
    __shared__ int lsum[256];
    int b = blockIdx.x, t = threadIdx.x;
    int base = b * 1024 + t * 4;
    int v[4];
    #pragma unroll
    for (int i = 0; i < 4; ++i) v[i] = (base + i < BINS_) ? cnt[base + i] : 0;
    int s = v[0] + v[1] + v[2] + v[3];
    lsum[t] = s;
    __syncthreads();
    for (int off = 1; off < 256; off <<= 1) {
        int x = (t >= off) ? lsum[t - off] : 0;
        __syncthreads();
        lsum[t] += x;
        __syncthreads();
    }
    int excl = lsum[t] - s;
    if (t == 255) blocksum[b] = lsum[255];
    #pragma unroll
    for (int i = 0; i < 4; ++i) {
        if (base + i < BINS_) bin_start[base + i] = excl;
        excl += v[i];
    }
}

__global__ void scanB_kernel(int* __restrict__ blocksum, int nb)
{
    if (threadIdx.x == 0 && blockIdx.x == 0) {
        int acc = 0;
        for (int b = 0; b < nb; ++b) { int v = blocksum[b]; blocksum[b] = acc; acc += v; }
    }
}

__global__ __launch_bounds__(256) void scanC_kernel(
    int* __restrict__ bin_start, const int* __restrict__ blocksum)
{
    int b = blockIdx.x, t = threadIdx.x;
    int off = blocksum[b];
    int base = b * 1024 + t * 4;
    #pragma unroll
    for (int i = 0; i < 4; ++i)
        if (base + i < BINS_) bin_start[base + i] += off;
    if (b == 0 && t == 0) bin_start[BINS_] = C_ * E_;
}

__global__ __launch_bounds__(256) void fill_kernel(
    const int* __restrict__ rows, const int* __restrict__ bin_start,
    int* __restrict__ cursor, int* __restrict__ perm)
{
    int eid = blockIdx.x * 256 + threadIdx.x;
    int c = eid / E_;
    int bin = rows[eid] * C_ + c;
    int pos = bin_start[bin] + atomicAdd(&cursor[bin], 1);
    perm[pos] = eid;
}

// ---------------------------------------------------------------------------
// gather (bf16): one wave per dest bin. Batch-load 64 edges' metadata into
// lanes (coalesced), broadcast via shfl; per edge one 4B bf16x2 load/lane.
// gfb[bin,:] = bf16( sum_e vals[e] * egob[cols[e], c, :] )
// ---------------------------------------------------------------------------
__global__ __launch_bounds__(256) void gather_kernel(
    const uint32_t* __restrict__ eg32, const float* __restrict__ vals,
    const int* __restrict__ cols, const int* __restrict__ bin_start,
    const int* __restrict__ perm, uint32_t* __restrict__ gfb32)
{
    int w = (int)(((size_t)blockIdx.x * 256 + threadIdx.x) >> 6);
    int lane = threadIdx.x & 63;
    w = __builtin_amdgcn_readfirstlane(w);
    int bs = bin_start[w], be = bin_start[w + 1];
    int c = w % C_;
    float2 acc = make_float2(0.f, 0.f);

    for (int base = bs; base < be; base += 64) {
        int cnt = be - base; if (cnt > 64) cnt = 64;
        float v = 0.f; int s = 0;
        if (lane < cnt) {
            int e = perm[base + lane];
            v = vals[e];
            s = cols[e];
        }
        for (int j = 0; j < cnt; j += 2) {
            float v0 = __shfl(v, j),     v1 = __shfl(v, j + 1);
            int   s0 = __shfl(s, j),     s1 = __shfl(s, j + 1);
            uint32_t m0 = eg32[((size_t)s0 * C_ + c) * (D_ / 2) + lane];
            uint32_t m1 = eg32[((size_t)s1 * C_ + c) * (D_ / 2) + lane];
            union { uint32_t u; float f; } a0, b0, a1, b1;
            a0.u = m0 << 16; b0.u = m0 & 0xffff0000u;
            a1.u = m1 << 16; b1.u = m1 & 0xffff0000u;
            acc.x = fmaf(v0, a0.f, acc.x); acc.y = fmaf(v0, b0.f, acc.y);
            acc.x = fmaf(v1, a1.f, acc.x); acc.y = fmaf(v1, b1.f, acc.y);
        }
    }
    uint32_t out = (uint32_t)(uint16_t)f2bf(acc.x) |
                   ((uint32_t)(uint16_t)f2bf(acc.y) << 16);
    gfb32[(size_t)w * (D_ / 2) + lane] = out;
}

// ---------------------------------------------------------------------------
// rowgemm via MFMA: stk = leaky((Xbf @ W * crit[row%5]) @ G)
// in: gfb bf16 row-major; out: stk fp32
// ---------------------------------------------------------------------------
__global__ __launch_bounds__(512, 4) void rowgemm_mfma_kernel(
    const short* __restrict__ gfb, float* __restrict__ stk,
    const short* __restrict__ Wf, const short* __restrict__ Gf,
    const float* __restrict__ critv)
{
    __shared__ short WGl[16384];        // W frags, then reused for G frags
    __shared__ float critl[C_ * D_];
    __shared__ short Zr[8 * 2048];      // per-wave 16x128 bf16, XOR-swizzled

    for (int i = threadIdx.x; i < 2048; i += 512)
        ((short8*)WGl)[i] = ((const short8*)Wf)[i];
    for (int i = threadIdx.x; i < C_ * D_; i += 512) critl[i] = critv[i];
    __syncthreads();

    int lane = threadIdx.x & 63, w = threadIdx.x >> 6;
    int g = lane >> 4, c15 = lane & 15;
    size_t r0 = (size_t)blockIdx.x * 128 + (size_t)w * 16;

    // A fragments: direct 16B bf16 loads
    short8 af[4];
    #pragma unroll
    for (int q = 0; q < 4; ++q)
        af[q] = *(const short8*)(gfb + (r0 + c15) * D_ + q * 32 + g * 8);

    f32x4 acc[8];
    #pragma unroll
    for (int t = 0; t < 8; ++t) acc[t] = (f32x4){0.f, 0.f, 0.f, 0.f};
    {
        const short8* Wp = (const short8*)WGl;
        #pragma unroll
        for (int t = 0; t < 8; ++t)
            #pragma unroll
            for (int q = 0; q < 4; ++q)
                acc[t] = __builtin_amdgcn_mfma_f32_16x16x32_bf16(
                    af[q], Wp[(t * 4 + q) * 64 + lane], acc[t], 0, 0, 0);
    }

    int rb = (int)r0 + g * 4;
    int cid[4];
    #pragma unroll
    for (int r = 0; r < 4; ++r) cid[r] = (rb + r) % C_;
    char* zw = (char*)&Zr[w * 2048];
    #pragma unroll
    for (int t = 0; t < 8; ++t)
        #pragma unroll
        for (int r = 0; r < 4; ++r) {
            float cv = critl[cid[r] * D_ + t * 16 + c15];
            float z = acc[t][r] * cv;
            int zrow = g * 4 + r;
            int cb = 32 * t + 2 * c15;
            int off = zrow * 256 + (cb ^ ((zrow & 7) << 4));
            *(short*)(zw + off) = f2bf(z);
        }
    __syncthreads();

    for (int i = threadIdx.x; i < 2048; i += 512)
        ((short8*)WGl)[i] = ((const short8*)Gf)[i];
    __syncthreads();

    short8 az[4];
    #pragma unroll
    for (int q = 0; q < 4; ++q) {
        int cb0 = 64 * q + 16 * g;
        int off = c15 * 256 + (cb0 ^ ((c15 & 7) << 4));
        az[q] = *(const short8*)(zw + off);
    }

    f32x4 acc2[8];
    #pragma unroll
    for (int t = 0; t < 8; ++t) acc2[t] = (f32x4){0.f, 0.f, 0.f, 0.f};
    {
        const short8* Gp = (const short8*)WGl;
        #pragma unroll
        for (int t = 0; t < 8; ++t)
            #pragma unroll
            for (int q = 0; q < 4; ++q)
                acc2[t] = __builtin_amdgcn_mfma_f32_16x16x32_bf16(
                    az[q], Gp[(t * 4 + q) * 64 + lane], acc2[t], 0, 0, 0);
    }

    #pragma unroll
    for (int t = 0; t < 8; ++t)
        #pragma unroll
        for (int r = 0; r < 4; ++r) {
            float s = acc2[t][r];
            s = s > 0.f ? s : 0.01f * s;
            stk[(r0 + (size_t)(g * 4 + r)) * D_ + t * 16 + c15] = s;
        }
}

// ---------------------------------------------------------------------------
// attention via MFMA; ego written as bf16, bank (fp32) += fp32 ego
// ---------------------------------------------------------------------------
__global__ __launch_bounds__(256, 3) void attn_mfma_kernel(
    const float* __restrict__ stk, const short* __restrict__ P1f,
    const float* __restrict__ p2, short* __restrict__ egob,
    float* __restrict__ bank, int last)
{
    __shared__ float4 S4l[80][32];      // swizzled: [row][f4 ^ (row&7)]
    __shared__ float rawl[80 * C_];
    __shared__ float wl[80 * C_];

    int tid = threadIdx.x;
    int lane = tid & 63, w = tid >> 6;
    int g = lane >> 4, c15 = lane & 15;
    int klo = (5 * w) >> 2;

    short8 Bf[5][4];
    float p2v[5];
    #pragma unroll
    for (int i = 0; i < 5; ++i) {
        int t = 5 * w + i;
        #pragma unroll
        for (int q = 0; q < 4; ++q)
            Bf[i][q] = ((const short8*)P1f)[(t * 4 + q) * 64 + lane];
        p2v[i] = p2[(t >> 2) * A_ + (t & 3) * 16 + c15];
    }

    const float4* buf4  = (const float4*)stk;
    float4*       bank4 = (float4*)bank;

    for (int grp = blockIdx.x; grp < N_ / 16; grp += gridDim.x) {
        size_t n0 = (size_t)grp * 16;
        __syncthreads();
        for (int idx = tid; idx < 2560; idx += 256) {
            int row = idx >> 5, f4 = idx & 31;
            S4l[row][f4 ^ (row & 7)] = buf4[(n0 * 5 + row) * 32 + f4];
        }
        for (int i = tid; i < 80 * C_; i += 256) rawl[i] = 0.f;
        __syncthreads();

        for (int rt = 0; rt < 5; ++rt) {
            short8 af[4];
            #pragma unroll
            for (int q = 0; q < 4; ++q) {
                int row = rt * 16 + c15;
                int f4a = 8 * q + 2 * g;
                float4 x0 = S4l[row][f4a ^ (row & 7)];
                float4 x1 = S4l[row][(f4a + 1) ^ (row & 7)];
                short8 a;
                a[0] = f2bf(x0.x); a[1] = f2bf(x0.y); a[2] = f2bf(x0.z); a[3] = f2bf(x0.w);
                a[4] = f2bf(x1.x); a[5] = f2bf(x1.y); a[6] = f2bf(x1.z); a[7] = f2bf(x1.w);
                af[q] = a;
            }
            f32x4 acc[5];
            #pragma unroll
            for (int i = 0; i < 5; ++i) acc[i] = (f32x4){0.f, 0.f, 0.f, 0.f};
            #pragma unroll
            for (int i = 0; i < 5; ++i)
                #pragma unroll
                for (int q = 0; q < 4; ++q)
                    acc[i] = __builtin_amdgcn_mfma_f32_16x16x32_bf16(
                        af[q], Bf[i][q], acc[i], 0, 0, 0);

            float2 ps[4];
            #pragma unroll
            for (int r = 0; r < 4; ++r) ps[r] = make_float2(0.f, 0.f);
            #pragma unroll
            for (int i = 0; i < 5; ++i) {
                int t = 5 * w + i;
                bool lo = (t >> 2) == klo;
                #pragma unroll
                for (int r = 0; r < 4; ++r) {
                    float x = acc[i][r];
                    float e = __expf(2.f * x);
                    float th = 1.f - 2.f * __builtin_amdgcn_rcpf(e + 1.f);
                    float con = th * p2v[i];
                    if (lo) ps[r].x += con; else ps[r].y += con;
                }
            }
            #pragma unroll
            for (int r = 0; r < 4; ++r) {
                #pragma unroll
                for (int m = 1; m < 16; m <<= 1) {
                    ps[r].x += __shfl_xor(ps[r].x, m);
                    ps[r].y += __shfl_xor(ps[r].y, m);
                }
                if (c15 == 0) {
                    int row = rt * 16 + g * 4 + r;
                    atomicAdd(&rawl[row * C_ + klo], ps[r].x);
                    atomicAdd(&rawl[row * C_ + klo + 1], ps[r].y);
                }
            }
        }
        __syncthreads();

        if (tid < 80) {
            int nl = tid / C_, k = tid % C_;
            float rv[C_];
            #pragma unroll
            for (int c = 0; c < C_; ++c) rv[c] = rawl[(nl * C_ + c) * C_ + k];
            float m = rv[0];
            #pragma unroll
            for (int c = 1; c < C_; ++c) m = fmaxf(m, rv[c]);
            float s = 0.f;
            #pragma unroll
            for (int c = 0; c < C_; ++c) { rv[c] = __expf(rv[c] - m); s += rv[c]; }
            float inv = __builtin_amdgcn_rcpf(s);
            #pragma unroll
            for (int c = 0; c < C_; ++c) wl[tid * C_ + c] = rv[c] * inv;
        }
        __syncthreads();

        #pragma unroll
        for (int ii = 0; ii < 10; ++ii) {
            int idx = tid + 256 * ii;
            int f4 = idx & 31;
            int nl = (idx >> 5) & 15, k = idx >> 9;
            float4 a = make_float4(0.f, 0.f, 0.f, 0.f);
            #pragma unroll
            for (int c = 0; c < C_; ++c) {
                float wv = wl[(nl * C_ + k) * C_ + c];
                int row = nl * C_ + c;
                float4 s = S4l[row][f4 ^ (row & 7)];
                a.x = fmaf(wv, s.x, a.x); a.y = fmaf(wv, s.y, a.y);
                a.z = fmaf(wv, s.z, a.z); a.w = fmaf(wv, s.w, a.w);
            }
            size_t go = ((n0 + nl) * 5 + k) * 32 + f4;
            float4 b = bank4[go];
            b.x += a.x; b.y += a.y; b.z += a.z; b.w += a.w;
            if (last) { b.x *= (1.f/3.f); b.y *= (1.f/3.f); b.z *= (1.f/3.f); b.w *= (1.f/3.f); }
            bank4[go] = b;
            short4v pk;
            pk[0] = f2bf(a.x); pk[1] = f2bf(a.y); pk[2] = f2bf(a.z); pk[3] = f2bf(a.w);
            *(short4v*)(egob + go * 4) = pk;
        }
    }
}

extern "C" void kernel_launch(void* const* d_in, const int* in_sizes, int n_in,
                              void* d_out, int out_size, void* d_ws, size_t ws_size,
                              hipStream_t stream) {
    const float* user  = (const float*)d_in[0];
    const float* item  = (const float*)d_in[1];
    const float* crit0 = (const float*)d_in[2];
    const float* W     = (const float*)d_in[3];
    const float* gl    = (const float*)d_in[4];
    const float* cl    = (const float*)d_in[5];
    const float* p1    = (const float*)d_in[6];
    const float* p2    = (const float*)d_in[7];
    const float* vals  = (const float*)d_in[8];
    const int*   rows  = (const int*)d_in[9];
    const int*   cols  = (const int*)d_in[10];

    float* out  = (float*)d_out;
    float* bank = out;
    float* crit_means = out + (size_t)(N_ + 1) * C_ * D_;

    const size_t NCD = (size_t)N_ * C_ * D_;
    short* egob  = (short*)d_ws;                        // N*C*D bf16
    short* gfb   = egob + NCD;                          // N*C*D bf16
    float* stk   = (float*)(gfb + NCD);                 // N*C*D fp32
    float* crit1 = stk + NCD;
    float* crit2 = crit1 + C_ * D_;
    short* Wf    = (short*)(crit2 + C_ * D_);           // 16384 bf16
    short* Gf    = Wf + (size_t)D_ * D_;                // 2 x 16384 bf16
    short* P1f   = Gf + 2 * (size_t)D_ * D_;            // 128*320 bf16
    int* bin_start = (int*)(P1f + (size_t)D_ * C_ * A_);
    int* cnt       = bin_start + BINS_ + 1;
    int* blocksum  = cnt + BINS_;
    int* perm      = blocksum + 512;

    init_kernel<<<(int)((NCD / 8 + 255) / 256), 256, 0, stream>>>(user, item, bank, egob);
    crit_kernel<<<1, 128, 0, stream>>>(crit0, cl, crit1, crit2, crit_means);
    prepack_kernel<<<24, 256, 0, stream>>>(W, gl, Wf, Gf);
    prepack_p1_kernel<<<80, 64, 0, stream>>>(p1, P1f);

    const int nbScan = (BINS_ + 1023) / 1024;
    hipMemsetAsync(cnt, 0, (size_t)BINS_ * sizeof(int), stream);
    hist_kernel<<<C_ * E_ / 256, 256, 0, stream>>>(rows, cnt);
    scanA_kernel<<<nbScan, 256, 0, stream>>>(cnt, bin_start, blocksum);
    scanB_kernel<<<1, 64, 0, stream>>>(blocksum, nbScan);
    scanC_kernel<<<nbScan, 256, 0, stream>>>(bin_start, blocksum);
    hipMemsetAsync(cnt, 0, (size_t)BINS_ * sizeof(int), stream);
    fill_kernel<<<C_ * E_ / 256, 256, 0, stream>>>(rows, bin_start, cnt, perm);

    for (int l = 0; l < L_; ++l) {
        gather_kernel<<<BINS_ * 64 / 256, 256, 0, stream>>>(
            (const uint32_t*)egob, vals, cols, bin_start, perm, (uint32_t*)gfb);
        rowgemm_mfma_kernel<<<N_ * C_ / 128, 512, 0, stream>>>(
            gfb, stk, Wf, Gf + (size_t)l * D_ * D_, l == 0 ? crit0 : crit1);
        attn_mfma_kernel<<<768, 256, 0, stream>>>(
            stk, P1f, p2, egob, bank, l == L_ - 1 ? 1 : 0);
    }
}

// Round 6
// 1654.177 us; speedup vs baseline: 16.3608x; 1.3364x over previous
//
#include <hip/hip_runtime.h>
#include <cstdint>
#include <cmath>

#define U_ 40000
#define I_ 40000
#define C_ 5
#define D_ 128
#define A_ 64
#define L_ 2
#define E_ 1280000
#define N_ (U_ + I_)
#define BINS_ (N_ * C_)

typedef __attribute__((ext_vector_type(8))) short short8;
typedef __attribute__((ext_vector_type(4))) short short4v;
typedef __attribute__((ext_vector_type(4))) float f32x4;

static __device__ __forceinline__ short f2bf(float f) {
    union { float f; uint32_t u; } x; x.f = f;
    uint32_t u = x.u;
    uint32_t r = (u + 0x7fffu + ((u >> 16) & 1u)) >> 16;   // RNE
    return (short)r;
}

// ---------------------------------------------------------------------------
// init: egob = bf16(concat(user, item)). (bank is written only by attn l=1)
// ---------------------------------------------------------------------------
__global__ __launch_bounds__(256) void init_kernel(
    const float* __restrict__ user, const float* __restrict__ item,
    short* __restrict__ egob)
{
    size_t i = (size_t)blockIdx.x * 256 + threadIdx.x;    // 8-float index
    const size_t total8 = (size_t)N_ * C_ * D_ / 8;
    const size_t user4  = (size_t)U_ * C_ * D_ / 4;
    if (i < total8) {
        size_t f4 = 2 * i;
        const float4* src = (f4 < user4) ? (const float4*)user
                                         : (const float4*)item - user4;
        float4 x0 = src[f4], x1 = src[f4 + 1];
        short8 p;
        p[0] = f2bf(x0.x); p[1] = f2bf(x0.y); p[2] = f2bf(x0.z); p[3] = f2bf(x0.w);
        p[4] = f2bf(x1.x); p[5] = f2bf(x1.y); p[6] = f2bf(x1.z); p[7] = f2bf(x1.w);
        ((short8*)egob)[i] = p;
    }
}

// ---------------------------------------------------------------------------
// crit chain + zero pad row of d_out
// ---------------------------------------------------------------------------
__global__ __launch_bounds__(128) void crit_kernel(
    const float* __restrict__ crit0, const float* __restrict__ clayers,
    float* __restrict__ crit1, float* __restrict__ crit2,
    float* __restrict__ crit_means, float* __restrict__ padrow)
{
    __shared__ float c0[C_ * D_], c1[C_ * D_], c2[C_ * D_];
    int t = threadIdx.x;
    for (int i = t; i < C_ * D_; i += 128) { c0[i] = crit0[i]; padrow[i] = 0.f; }
    __syncthreads();
    for (int c = 0; c < C_; ++c) {
        float acc = 0.f;
        for (int d = 0; d < D_; ++d) acc = fmaf(c0[c * D_ + d], clayers[d * D_ + t], acc);
        c1[c * D_ + t] = acc;
    }
    __syncthreads();
    for (int c = 0; c < C_; ++c) {
        float acc = 0.f;
        for (int d = 0; d < D_; ++d) acc = fmaf(c1[c * D_ + d], clayers[D_ * D_ + d * D_ + t], acc);
        c2[c * D_ + t] = acc;
    }
    __syncthreads();
    for (int i = t; i < C_ * D_; i += 128) {
        crit1[i] = c1[i];
        crit2[i] = c2[i];
        crit_means[i] = (c0[i] + c1[i] + c2[i]) * (1.0f / 3.0f);
    }
}

// ---------------------------------------------------------------------------
// prepack W / G0 / G1 into bf16 B-fragment layout (mfma_f32_16x16x32_bf16)
// ---------------------------------------------------------------------------
__global__ __launch_bounds__(256) void prepack_kernel(
    const float* __restrict__ W, const float* __restrict__ gl,
    short* __restrict__ Wf, short* __restrict__ Gf)
{
    int b = blockIdx.x;               // 0..23: matrix = b>>3, t = b&7
    int m = b >> 3, t = b & 7;
    int q = threadIdx.x >> 6, l = threadIdx.x & 63;
    int g = l >> 4, c15 = l & 15;
    const float* src = (m == 0) ? W : gl + (size_t)(m - 1) * D_ * D_;
    short*       dst = (m == 0) ? Wf : Gf + (size_t)(m - 1) * D_ * D_;
    short8 v;
    #pragma unroll
    for (int j = 0; j < 8; ++j) {
        int k = q * 32 + g * 8 + j;
        int n = t * 16 + c15;
        v[j] = f2bf(src[k * D_ + n]);
    }
    *(short8*)(dst + (((t * 4 + q) * 64 + l) << 3)) = v;
}

// ---------------------------------------------------------------------------
// prepack p1 (C,D,A) as B-frags of P1all (128 x 320)
// ---------------------------------------------------------------------------
__global__ __launch_bounds__(64) void prepack_p1_kernel(
    const float* __restrict__ p1, short* __restrict__ P1f)
{
    int t = blockIdx.x >> 2, q = blockIdx.x & 3;   // 80 blocks
    int lane = threadIdx.x;
    int g = lane >> 4, c15 = lane & 15;
    int k = t >> 2, a = (t & 3) * 16 + c15;
    short8 v;
    #pragma unroll
    for (int j = 0; j < 8; ++j) {
        int d = q * 32 + g * 8 + j;
        v[j] = f2bf(p1[((size_t)k * D_ + d) * A_ + a]);
    }
    *(short8*)(P1f + (((t * 4 + q) * 64 + lane) << 3)) = v;
}

// ---------------------------------------------------------------------------
// CSR build
// ---------------------------------------------------------------------------
__global__ __launch_bounds__(256) void hist_kernel(
    const int* __restrict__ rows, int* __restrict__ cnt)
{
    int eid = blockIdx.x * 256 + threadIdx.x;
    int c = eid / E_;
    int bin = rows[eid] * C_ + c;
    atomicAdd(&cnt[bin], 1);
}

__global__ __launch_bounds__(256) void scanA_kernel(
    const int* __restrict__ cnt, int* __restrict__ bin_start,
    int* __restrict__ blocksum)
{
    __shared__ int lsum[256];
    int b = blockIdx.x, t = threadIdx.x;
    int base = b * 1024 + t * 4;
    int v[4];
    #pragma unroll
    for (int i = 0; i < 4; ++i) v[i] = (base + i < BINS_) ? cnt[base + i] : 0;
    int s = v[0] + v[1] + v[2] + v[3];
    lsum[t] = s;
    __syncthreads();
    for (int off = 1; off < 256; off <<= 1) {
        int x = (t >= off) ? lsum[t - off] : 0;
        __syncthreads();
        lsum[t] += x;
        __syncthreads();
    }
    int excl = lsum[t] - s;
    if (t == 255) blocksum[b] = lsum[255];
    #pragma unroll
    for (int i = 0; i < 4; ++i) {
        if (base + i < BINS_) bin_start[base + i] = excl;
        excl += v[i];
    }
}

__global__ void scanB_kernel(int* __restrict__ blocksum, int nb)
{
    if (threadIdx.x == 0 && blockIdx.x == 0) {
        int acc = 0;
        for (int b = 0; b < nb; ++b) { int v = blocksum[b]; blocksum[b] = acc; acc += v; }
    }
}

__global__ __launch_bounds__(256) void scanC_kernel(
    int* __restrict__ bin_start, const int* __restrict__ blocksum)
{
    int b = blockIdx.x, t = threadIdx.x;
    int off = blocksum[b];
    int base = b * 1024 + t * 4;
    #pragma unroll
    for (int i = 0; i < 4; ++i)
        if (base + i < BINS_) bin_start[base + i] += off;
    if (b == 0 && t == 0) bin_start[BINS_] = C_ * E_;
}

// fill: read rows/vals/cols coalesced by eid; write packed (val,col) at CSR pos
__global__ __launch_bounds__(256) void fill_kernel(
    const int* __restrict__ rows, const float* __restrict__ vals,
    const int* __restrict__ cols, const int* __restrict__ bin_start,
    int* __restrict__ cursor, uint2* __restrict__ vc)
{
    int eid = blockIdx.x * 256 + threadIdx.x;
    int c = eid / E_;
    int bin = rows[eid] * C_ + c;
    int pos = bin_start[bin] + atomicAdd(&cursor[bin], 1);
    union { float f; uint32_t u; } t; t.f = vals[eid];
    uint2 m; m.x = t.u; m.y = (uint32_t)cols[eid];
    vc[pos] = m;
}

// ---------------------------------------------------------------------------
// gather (bf16): one wave per dest bin. Streamed (val,col) metadata,
// half-wave edge split: lane owns 4 dims (8B); lanes<32 do even-position
// edges, lanes>=32 odd; 4 edges (2 loads) in flight per iteration.
// ---------------------------------------------------------------------------
__global__ __launch_bounds__(256) void gather_kernel(
    const uint2* __restrict__ eg64, const uint2* __restrict__ vc,
    const int* __restrict__ bin_start, uint2* __restrict__ gfb64)
{
    int w = (int)(((size_t)blockIdx.x * 256 + threadIdx.x) >> 6);
    int lane = threadIdx.x & 63;
    w = __builtin_amdgcn_readfirstlane(w);
    int bs = bin_start[w], be = bin_start[w + 1];
    int c = w % C_;
    int half = lane >> 5, l31 = lane & 31;
    float a0 = 0.f, a1 = 0.f, a2 = 0.f, a3 = 0.f;

    for (int base = bs; base < be; base += 64) {
        int cnt = be - base; if (cnt > 64) cnt = 64;
        float v = 0.f; int s = 0;
        if (lane < cnt) {
            uint2 m = vc[base + lane];
            union { uint32_t u; float f; } t; t.u = m.x;
            v = t.f; s = (int)m.y;
        }
        for (int j = 0; j < cnt; j += 4) {
            int iA = j + half, iB = j + 2 + half;
            float vA = __shfl(v, iA), vB = __shfl(v, iB);
            int   sA = __shfl(s, iA), sB = __shfl(s, iB);
            uint2 mA = eg64[((size_t)sA * C_ + c) * (D_ / 4) + l31];
            uint2 mB = eg64[((size_t)sB * C_ + c) * (D_ / 4) + l31];
            union { uint32_t u; float f; } t;
            t.u = mA.x << 16;         a0 = fmaf(vA, t.f, a0);
            t.u = mA.x & 0xffff0000u; a1 = fmaf(vA, t.f, a1);
            t.u = mA.y << 16;         a2 = fmaf(vA, t.f, a2);
            t.u = mA.y & 0xffff0000u; a3 = fmaf(vA, t.f, a3);
            t.u = mB.x << 16;         a0 = fmaf(vB, t.f, a0);
            t.u = mB.x & 0xffff0000u; a1 = fmaf(vB, t.f, a1);
            t.u = mB.y << 16;         a2 = fmaf(vB, t.f, a2);
            t.u = mB.y & 0xffff0000u; a3 = fmaf(vB, t.f, a3);
        }
    }
    a0 += __shfl_xor(a0, 32);
    a1 += __shfl_xor(a1, 32);
    a2 += __shfl_xor(a2, 32);
    a3 += __shfl_xor(a3, 32);
    if (lane < 32) {
        uint2 o;
        o.x = (uint32_t)(uint16_t)f2bf(a0) | ((uint32_t)(uint16_t)f2bf(a1) << 16);
        o.y = (uint32_t)(uint16_t)f2bf(a2) | ((uint32_t)(uint16_t)f2bf(a3) << 16);
        gfb64[(size_t)w * (D_ / 4) + l31] = o;
    }
}

// ---------------------------------------------------------------------------
// rowgemm via MFMA: stk = leaky((Xbf @ W * crit[row%5]) @ G)
// ---------------------------------------------------------------------------
__global__ __launch_bounds__(512, 4) void rowgemm_mfma_kernel(
    const short* __restrict__ gfb, float* __restrict__ stk,
    const short* __restrict__ Wf, const short* __restrict__ Gf,
    const float* __restrict__ critv)
{
    __shared__ short WGl[16384];        // W frags, then reused for G frags
    __shared__ float critl[C_ * D_];
    __shared__ short Zr[8 * 2048];      // per-wave 16x128 bf16, XOR-swizzled

    for (int i = threadIdx.x; i < 2048; i += 512)
        ((short8*)WGl)[i] = ((const short8*)Wf)[i];
    for (int i = threadIdx.x; i < C_ * D_; i += 512) critl[i] = critv[i];
    __syncthreads();

    int lane = threadIdx.x & 63, w = threadIdx.x >> 6;
    int g = lane >> 4, c15 = lane & 15;
    size_t r0 = (size_t)blockIdx.x * 128 + (size_t)w * 16;

    short8 af[4];
    #pragma unroll
    for (int q = 0; q < 4; ++q)
        af[q] = *(const short8*)(gfb + (r0 + c15) * D_ + q * 32 + g * 8);

    f32x4 acc[8];
    #pragma unroll
    for (int t = 0; t < 8; ++t) acc[t] = (f32x4){0.f, 0.f, 0.f, 0.f};
    {
        const short8* Wp = (const short8*)WGl;
        #pragma unroll
        for (int t = 0; t < 8; ++t)
            #pragma unroll
            for (int q = 0; q < 4; ++q)
                acc[t] = __builtin_amdgcn_mfma_f32_16x16x32_bf16(
                    af[q], Wp[(t * 4 + q) * 64 + lane], acc[t], 0, 0, 0);
    }

    int rb = (int)r0 + g * 4;
    int cid[4];
    #pragma unroll
    for (int r = 0; r < 4; ++r) cid[r] = (rb + r) % C_;
    char* zw = (char*)&Zr[w * 2048];
    #pragma unroll
    for (int t = 0; t < 8; ++t)
        #pragma unroll
        for (int r = 0; r < 4; ++r) {
            float cv = critl[cid[r] * D_ + t * 16 + c15];
            float z = acc[t][r] * cv;
            int zrow = g * 4 + r;
            int cb = 32 * t + 2 * c15;
            int off = zrow * 256 + (cb ^ ((zrow & 7) << 4));
            *(short*)(zw + off) = f2bf(z);
        }
    __syncthreads();

    for (int i = threadIdx.x; i < 2048; i += 512)
        ((short8*)WGl)[i] = ((const short8*)Gf)[i];
    __syncthreads();

    short8 az[4];
    #pragma unroll
    for (int q = 0; q < 4; ++q) {
        int cb0 = 64 * q + 16 * g;
        int off = c15 * 256 + (cb0 ^ ((c15 & 7) << 4));
        az[q] = *(const short8*)(zw + off);
    }

    f32x4 acc2[8];
    #pragma unroll
    for (int t = 0; t < 8; ++t) acc2[t] = (f32x4){0.f, 0.f, 0.f, 0.f};
    {
        const short8* Gp = (const short8*)WGl;
        #pragma unroll
        for (int t = 0; t < 8; ++t)
            #pragma unroll
            for (int q = 0; q < 4; ++q)
                acc2[t] = __builtin_amdgcn_mfma_f32_16x16x32_bf16(
                    az[q], Gp[(t * 4 + q) * 64 + lane], acc2[t], 0, 0, 0);
    }

    #pragma unroll
    for (int t = 0; t < 8; ++t)
        #pragma unroll
        for (int r = 0; r < 4; ++r) {
            float s = acc2[t][r];
            s = s > 0.f ? s : 0.01f * s;
            stk[(r0 + (size_t)(g * 4 + r)) * D_ + t * 16 + c15] = s;
        }
}

// ---------------------------------------------------------------------------
// attention via MFMA.
//   l=0: write egob = bf16(ego0) only (no bank traffic)
//   l=1: bank = (init + ego0 + ego1) / 3  (init from user/item, ego0 from egob)
// ---------------------------------------------------------------------------
__global__ __launch_bounds__(256, 3) void attn_mfma_kernel(
    const float* __restrict__ stk, const short* __restrict__ P1f,
    const float* __restrict__ p2, const float* __restrict__ user,
    const float* __restrict__ item, short* __restrict__ egob,
    float* __restrict__ bank, int last)
{
    __shared__ float4 S4l[80][32];      // swizzled: [row][f4 ^ (row&7)]
    __shared__ float rawl[80 * C_];
    __shared__ float wl[80 * C_];

    int tid = threadIdx.x;
    int lane = tid & 63, w = tid >> 6;
    int g = lane >> 4, c15 = lane & 15;
    int klo = (5 * w) >> 2;

    short8 Bf[5][4];
    float p2v[5];
    #pragma unroll
    for (int i = 0; i < 5; ++i) {
        int t = 5 * w + i;
        #pragma unroll
        for (int q = 0; q < 4; ++q)
            Bf[i][q] = ((const short8*)P1f)[(t * 4 + q) * 64 + lane];
        p2v[i] = p2[(t >> 2) * A_ + (t & 3) * 16 + c15];
    }

    const float4* buf4  = (const float4*)stk;
    float4*       bank4 = (float4*)bank;
    const float4* user4 = (const float4*)user;
    const float4* item4 = (const float4*)item;

    for (int grp = blockIdx.x; grp < N_ / 16; grp += gridDim.x) {
        size_t n0 = (size_t)grp * 16;
        __syncthreads();
        for (int idx = tid; idx < 2560; idx += 256) {
            int row = idx >> 5, f4 = idx & 31;
            S4l[row][f4 ^ (row & 7)] = buf4[(n0 * 5 + row) * 32 + f4];
        }
        for (int i = tid; i < 80 * C_; i += 256) rawl[i] = 0.f;
        __syncthreads();

        for (int rt = 0; rt < 5; ++rt) {
            short8 af[4];
            #pragma unroll
            for (int q = 0; q < 4; ++q) {
                int row = rt * 16 + c15;
                int f4a = 8 * q + 2 * g;
                float4 x0 = S4l[row][f4a ^ (row & 7)];
                float4 x1 = S4l[row][(f4a + 1) ^ (row & 7)];
                short8 a;
                a[0] = f2bf(x0.x); a[1] = f2bf(x0.y); a[2] = f2bf(x0.z); a[3] = f2bf(x0.w);
                a[4] = f2bf(x1.x); a[5] = f2bf(x1.y); a[6] = f2bf(x1.z); a[7] = f2bf(x1.w);
                af[q] = a;
            }
            f32x4 acc[5];
            #pragma unroll
            for (int i = 0; i < 5; ++i) acc[i] = (f32x4){0.f, 0.f, 0.f, 0.f};
            #pragma unroll
            for (int i = 0; i < 5; ++i)
                #pragma unroll
                for (int q = 0; q < 4; ++q)
                    acc[i] = __builtin_amdgcn_mfma_f32_16x16x32_bf16(
                        af[q], Bf[i][q], acc[i], 0, 0, 0);

            float2 ps[4];
            #pragma unroll
            for (int r = 0; r < 4; ++r) ps[r] = make_float2(0.f, 0.f);
            #pragma unroll
            for (int i = 0; i < 5; ++i) {
                int t = 5 * w + i;
                bool lo = (t >> 2) == klo;
                #pragma unroll
                for (int r = 0; r < 4; ++r) {
                    float x = acc[i][r];
                    float e = __expf(2.f * x);
                    float th = 1.f - 2.f * __builtin_amdgcn_rcpf(e + 1.f);
                    float con = th * p2v[i];
                    if (lo) ps[r].x += con; else ps[r].y += con;
                }
            }
            #pragma unroll
            for (int r = 0; r < 4; ++r) {
                #pragma unroll
                for (int m = 1; m < 16; m <<= 1) {
                    ps[r].x += __shfl_xor(ps[r].x, m);
                    ps[r].y += __shfl_xor(ps[r].y, m);
                }
                if (c15 == 0) {
                    int row = rt * 16 + g * 4 + r;
                    atomicAdd(&rawl[row * C_ + klo], ps[r].x);
                    atomicAdd(&rawl[row * C_ + klo + 1], ps[r].y);
                }
            }
        }
        __syncthreads();

        if (tid < 80) {
            int nl = tid / C_, k = tid % C_;
            float rv[C_];
            #pragma unroll
            for (int c = 0; c < C_; ++c) rv[c] = rawl[(nl * C_ + c) * C_ + k];
            float m = rv[0];
            #pragma unroll
            for (int c = 1; c < C_; ++c) m = fmaxf(m, rv[c]);
            float s = 0.f;
            #pragma unroll
            for (int c = 0; c < C_; ++c) { rv[c] = __expf(rv[c] - m); s += rv[c]; }
            float inv = __builtin_amdgcn_rcpf(s);
            #pragma unroll
            for (int c = 0; c < C_; ++c) wl[tid * C_ + c] = rv[c] * inv;
        }
        __syncthreads();

        #pragma unroll
        for (int ii = 0; ii < 10; ++ii) {
            int idx = tid + 256 * ii;
            int f4 = idx & 31;
            int nl = (idx >> 5) & 15, k = idx >> 9;
            float4 a = make_float4(0.f, 0.f, 0.f, 0.f);
            #pragma unroll
            for (int c = 0; c < C_; ++c) {
                float wv = wl[(nl * C_ + k) * C_ + c];
                int row = nl * C_ + c;
                float4 s = S4l[row][f4 ^ (row & 7)];
                a.x = fmaf(wv, s.x, a.x); a.y = fmaf(wv, s.y, a.y);
                a.z = fmaf(wv, s.z, a.z); a.w = fmaf(wv, s.w, a.w);
            }
            size_t n = n0 + nl;
            size_t go = (n * 5 + k) * 32 + f4;
            if (!last) {
                short4v pk;
                pk[0] = f2bf(a.x); pk[1] = f2bf(a.y); pk[2] = f2bf(a.z); pk[3] = f2bf(a.w);
                *(short4v*)(egob + go * 4) = pk;
            } else {
                uint2 e0 = *(const uint2*)(egob + go * 4);
                union { uint32_t u; float f; } t;
                float4 b = (n < U_) ? user4[((size_t)n * C_ + k) * 32 + f4]
                                    : item4[((size_t)(n - U_) * C_ + k) * 32 + f4];
                t.u = e0.x << 16;         b.x += t.f + a.x;
                t.u = e0.x & 0xffff0000u; b.y += t.f + a.y;
                t.u = e0.y << 16;         b.z += t.f + a.z;
                t.u = e0.y & 0xffff0000u; b.w += t.f + a.w;
                b.x *= (1.f / 3.f); b.y *= (1.f / 3.f);
                b.z *= (1.f / 3.f); b.w *= (1.f / 3.f);
                bank4[go] = b;
            }
        }
    }
}

extern "C" void kernel_launch(void* const* d_in, const int* in_sizes, int n_in,
                              void* d_out, int out_size, void* d_ws, size_t ws_size,
                              hipStream_t stream) {
    const float* user  = (const float*)d_in[0];
    const float* item  = (const float*)d_in[1];
    const float* crit0 = (const float*)d_in[2];
    const float* W     = (const float*)d_in[3];
    const float* gl    = (const float*)d_in[4];
    const float* cl    = (const float*)d_in[5];
    const float* p1    = (const float*)d_in[6];
    const float* p2    = (const float*)d_in[7];
    const float* vals  = (const float*)d_in[8];
    const int*   rows  = (const int*)d_in[9];
    const int*   cols  = (const int*)d_in[10];

    float* out  = (float*)d_out;
    float* bank = out;
    float* padrow = out + (size_t)N_ * C_ * D_;
    float* crit_means = out + (size_t)(N_ + 1) * C_ * D_;

    const size_t NCD = (size_t)N_ * C_ * D_;
    short* egob  = (short*)d_ws;                        // N*C*D bf16
    short* gfb   = egob + NCD;                          // N*C*D bf16
    float* stk   = (float*)(gfb + NCD);                 // N*C*D fp32
    float* crit1 = stk + NCD;
    float* crit2 = crit1 + C_ * D_;
    short* Wf    = (short*)(crit2 + C_ * D_);           // 16384 bf16
    short* Gf    = Wf + (size_t)D_ * D_;                // 2 x 16384 bf16
    short* P1f   = Gf + 2 * (size_t)D_ * D_;            // 128*320 bf16
    int* bin_start = (int*)(P1f + (size_t)D_ * C_ * A_);   // BINS_+2 (8B-align next)
    int* cnt       = bin_start + BINS_ + 2;
    int* blocksum  = cnt + BINS_;
    uint2* vc      = (uint2*)(blocksum + 512);          // C*E packed (val,col)

    init_kernel<<<(int)((NCD / 8 + 255) / 256), 256, 0, stream>>>(user, item, egob);
    crit_kernel<<<1, 128, 0, stream>>>(crit0, cl, crit1, crit2, crit_means, padrow);
    prepack_kernel<<<24, 256, 0, stream>>>(W, gl, Wf, Gf);
    prepack_p1_kernel<<<80, 64, 0, stream>>>(p1, P1f);

    const int nbScan = (BINS_ + 1023) / 1024;
    hipMemsetAsync(cnt, 0, (size_t)BINS_ * sizeof(int), stream);
    hist_kernel<<<C_ * E_ / 256, 256, 0, stream>>>(rows, cnt);
    scanA_kernel<<<nbScan, 256, 0, stream>>>(cnt, bin_start, blocksum);
    scanB_kernel<<<1, 64, 0, stream>>>(blocksum, nbScan);
    scanC_kernel<<<nbScan, 256, 0, stream>>>(bin_start, blocksum);
    hipMemsetAsync(cnt, 0, (size_t)BINS_ * sizeof(int), stream);
    fill_kernel<<<C_ * E_ / 256, 256, 0, stream>>>(rows, vals, cols, bin_start, cnt, vc);

    for (int l = 0; l < L_; ++l) {
        gather_kernel<<<BINS_ / 4, 256, 0, stream>>>(
            (const uint2*)egob, vc, bin_start, (uint2*)gfb);
        rowgemm_mfma_kernel<<<N_ * C_ / 128, 512, 0, stream>>>(
            gfb, stk, Wf, Gf + (size_t)l * D_ * D_, l == 0 ? crit0 : crit1);
        attn_mfma_kernel<<<768, 256, 0, stream>>>(
            stk, P1f, p2, user, item, egob, bank, l == L_ - 1 ? 1 : 0);
    }
}